// Round 2
// baseline (880.910 us; speedup 1.0000x reference)
//
#include <hip/hip_runtime.h>
#include <hip/hip_bf16.h>
#include <stdint.h>

#define TOTAL 4096
#define EMB 384
#define MD 32
#define NDOCS (TOTAL - 1 - MD)   // 4063
#define LN_EPS 1e-5f

typedef __hip_bfloat16 bf16;

// Dual-dtype load: inputs may be stored bf16 or fp32; isbf selects at runtime.
__device__ __forceinline__ float ldf(const void* p, int i, int isbf) {
    return isbf ? __bfloat162float(((const bf16*)p)[i]) : ((const float*)p)[i];
}

// ---------------- detect storage dtype of float inputs --------------------------------
// bf16 storage: even-indexed u16 words are bf16 of N(0,1) -> exponent in [100,140] ~100%.
// fp32 storage: even-indexed u16 words are low mantissa bits -> uniform, ~16% hit.
__global__ void k_detect(const uint16_t* p, int* flag) {
    __shared__ int red[4];
    int t = threadIdx.x;
    int cnt = 0;
    for (int k = t; k < 4096; k += 256) {
        uint16_t w = p[2 * k];
        int e = (w >> 7) & 0xFF;
        if (e >= 100 && e <= 140) cnt++;
    }
    for (int o = 32; o > 0; o >>= 1) cnt += __shfl_down(cnt, o);
    if ((t & 63) == 0) red[t >> 6] = cnt;
    __syncthreads();
    if (t == 0) flag[0] = (red[0] + red[1] + red[2] + red[3] > 2048) ? 1 : 0;
}

// ---------------- transpose weights (-> fp32, transposed for coalesced reads) ---------
__global__ void k_transpose(const void* proj_w, const void* gat_W, const void* fusion_w,
                            float* projT, float* gatT, float* fwT, const int* flagp) {
    int isbf = flagp[0];
    int idx = blockIdx.x * 256 + threadIdx.x;
    if (idx < EMB * 256) {                      // projT[d*256+c] = proj_w[c*EMB+d]
        int d = idx >> 8, c = idx & 255;
        projT[idx] = ldf(proj_w, c * EMB + d, isbf);
    } else if (idx < EMB * 256 + 2 * 256 * 256) {
        int r = idx - EMB * 256;
        int l = r >> 16; int rem = r & 65535;
        int d = rem >> 8, c = rem & 255;        // gatT[l][d*256+c] = gat_W[l][c*256+d]
        gatT[r] = ldf(gat_W, l * 65536 + c * 256 + d, isbf);
    } else if (idx < EMB * 256 + 2 * 256 * 256 + 514 * 256) {
        int r = idx - (EMB * 256 + 2 * 256 * 256);
        int j = r >> 8, c = r & 255;            // fwT[j*256+c] = fusion_w[c*514+j]
        fwT[r] = ldf(fusion_w, c * 514 + j, isbf);
    }
}

// ---------------- adj -> per-row bitmask (bit set = edge present) --------------------
__global__ void k_adjmask(const int* adj, unsigned long long* maskb) {
    int i = blockIdx.x;
    int t = threadIdx.x;
    int w = t >> 6, l = t & 63;
    for (int c = w; c < 64; c += 4) {
        int a = adj[(size_t)i * TOTAL + c * 64 + l];
        unsigned long long m = __ballot(a != 0);
        if (l == 0) maskb[i * 64 + c] = m;
    }
}

// ---------------- h = relu(emb @ projT + b), 8 rows/block -----------------------------
#define PR 8
__global__ void k_proj(const void* emb, const void* proj_b, const float* projT, float* h,
                       const int* flagp) {
    __shared__ float xs[PR][EMB];
    int isbf = flagp[0];
    int i0 = blockIdx.x * PR, t = threadIdx.x;
    for (int idx = t; idx < PR * EMB; idx += 256) {
        int r = idx / EMB, d = idx % EMB;
        xs[r][d] = ldf(emb, (i0 + r) * EMB + d, isbf);
    }
    __syncthreads();
    float acc[PR];
    float bias = ldf(proj_b, t, isbf);
#pragma unroll
    for (int r = 0; r < PR; r++) acc[r] = bias;
    for (int d = 0; d < EMB; d++) {
        float wv = projT[d * 256 + t];
#pragma unroll
        for (int r = 0; r < PR; r++) acc[r] = fmaf(xs[r][d], wv, acc[r]);
    }
#pragma unroll
    for (int r = 0; r < PR; r++) h[(size_t)(i0 + r) * 256 + t] = fmaxf(acc[r], 0.f);
}

// ---------------- query-aware doc update: s += 0.8*cos(q,s)*q ------------------------
__global__ void k_cosupdate(float* h) {
    __shared__ float red[12];
    int n = blockIdx.x, t = threadIdx.x;
    int row = 1 + MD + n;
    float qv = h[t];
    float sv = h[(size_t)row * 256 + t];
    float a = qv * qv, b = sv * sv, c = qv * sv;
    for (int o = 32; o > 0; o >>= 1) {
        a += __shfl_down(a, o); b += __shfl_down(b, o); c += __shfl_down(c, o);
    }
    int w = t >> 6;
    if ((t & 63) == 0) { red[w] = a; red[4 + w] = b; red[8 + w] = c; }
    __syncthreads();
    float qq = red[0] + red[1] + red[2] + red[3];
    float ss = red[4] + red[5] + red[6] + red[7];
    float qs = red[8] + red[9] + red[10] + red[11];
    float cosv = qs / ((sqrtf(qq) + 1e-8f) * (sqrtf(ss) + 1e-8f));
    h[(size_t)row * 256 + t] = sv + 0.8f * cosv * qv;
}

// ---------------- layernorm + Wh GEMM + src/dst projections, 4 rows/block -------------
#define LR 4
__global__ void k_ln_wh(const float* h, const float* gatT, const void* ln_scale,
                        const void* ln_bias, const void* gat_a,
                        float* wh, float* srcb, float* dstb, int layer, const int* flagp) {
    __shared__ float xs[LR][256];
    __shared__ float red[2][LR][4];
    int isbf = flagp[0];
    int i0 = blockIdx.x * LR, t = threadIdx.x;
    int w = t >> 6, l = t & 63;
    float scale = ldf(ln_scale, layer * 256 + t, isbf);
    float bias = ldf(ln_bias, layer * 256 + t, isbf);
    float hv[LR];
#pragma unroll
    for (int r = 0; r < LR; r++) hv[r] = h[(size_t)(i0 + r) * 256 + t];
#pragma unroll
    for (int r = 0; r < LR; r++) {
        float a = hv[r], b = hv[r] * hv[r];
        for (int o = 32; o > 0; o >>= 1) { a += __shfl_down(a, o); b += __shfl_down(b, o); }
        if (l == 0) { red[0][r][w] = a; red[1][r][w] = b; }
    }
    __syncthreads();
#pragma unroll
    for (int r = 0; r < LR; r++) {
        float mu = (red[0][r][0] + red[0][r][1] + red[0][r][2] + red[0][r][3]) * (1.f / 256.f);
        float var = (red[1][r][0] + red[1][r][1] + red[1][r][2] + red[1][r][3]) * (1.f / 256.f) - mu * mu;
        float x = (hv[r] - mu) * rsqrtf(var + LN_EPS) * scale + bias;
        xs[r][t] = x;
    }
    __syncthreads();
    const float* gT = gatT + layer * 65536;
    float acc[LR] = {0.f, 0.f, 0.f, 0.f};
    for (int d = 0; d < 256; d++) {
        float wv = gT[d * 256 + t];
#pragma unroll
        for (int r = 0; r < LR; r++) acc[r] = fmaf(xs[r][d], wv, acc[r]);
    }
    float av1 = ldf(gat_a, layer * 512 + w * 128 + l, isbf);
    float av2 = ldf(gat_a, layer * 512 + w * 128 + 64 + l, isbf);
#pragma unroll
    for (int r = 0; r < LR; r++) {
        wh[(size_t)(i0 + r) * 256 + t] = acc[r];
        float sv = acc[r] * av1, dv = acc[r] * av2;
        for (int o = 32; o > 0; o >>= 1) { sv += __shfl_down(sv, o); dv += __shfl_down(dv, o); }
        if (l == 0) { srcb[w * 4096 + i0 + r] = sv; dstb[w * 4096 + i0 + r] = dv; }
    }
}

// ---------------- online softmax stats per (row, head): m and 1/l ---------------------
__global__ void k_stats(const float* srcb, const float* dstb, const unsigned long long* maskb,
                        float* mrow, float* lrow) {
    __shared__ unsigned long long mb[64];
    int i = blockIdx.x, t = threadIdx.x;
    if (t < 64) mb[t] = maskb[i * 64 + t];
    __syncthreads();
    int w = t >> 6, l = t & 63;
    float si = srcb[w * 4096 + i];
    const float* dp = dstb + w * 4096;
    float m = -__builtin_inff(), s = 0.f;
    for (int c = 0; c < 64; c++) {
        float e = si + dp[c * 64 + l];
        e = e > 0.f ? e : 0.2f * e;
        if ((mb[c] >> l) & 1ull) {
            float M = fmaxf(m, e);                       // e finite, so M finite
            s = s * __expf(fminf(m - M, 0.f)) + __expf(e - M);
            m = M;
        }
    }
    for (int o = 1; o < 64; o <<= 1) {
        float m2 = __shfl_xor(m, o), s2 = __shfl_xor(s, o);
        float M = fmaxf(m, m2);
        // fminf(NaN,0)=0 on AMD -> branchless, -inf-proof merge
        s = s * __expf(fminf(m - M, 0.f)) + s2 * __expf(fminf(m2 - M, 0.f));
        m = M;
    }
    if (l == 0) { mrow[w * 4096 + i] = m; lrow[w * 4096 + i] = 1.f / s; }
}

// ---------------- PV: hn[i,c] = sum_j p(i,h(c),j) * Wh[j,c] ---------------------------
#define TI 16
#define JS 4
#define JSLICE (TOTAL / JS)
__global__ __launch_bounds__(256) void k_pv(const float* wh, const float* srcb,
                                            const float* dstb, const float* mrow,
                                            const float* lrow,
                                            const unsigned long long* maskb, float* hnew) {
    __shared__ float Whs[32][256];
    __shared__ float ps[TI][4][33];
    __shared__ float dsts[4][32];
    __shared__ unsigned long long mb[TI][16];
    __shared__ float ssrc[TI][4], sm[TI][4], sinv[TI][4];
    int t = threadIdx.x;
    int i0 = blockIdx.x * TI;
    int jbase = blockIdx.y * JSLICE;
    if (t < TI * 4) {
        int r = t >> 2, hh = t & 3;
        ssrc[r][hh] = srcb[hh * 4096 + i0 + r];
        sm[r][hh]   = mrow[hh * 4096 + i0 + r];
        sinv[r][hh] = lrow[hh * 4096 + i0 + r];
    }
    {
        int r = t >> 4, wq = t & 15;
        mb[r][wq] = maskb[(size_t)(i0 + r) * 64 + (jbase >> 6) + wq];
    }
    int w = t >> 6, l = t & 63;
    int hc = l >> 4;
    int cb = l * 4;
    float acc[4][4];
#pragma unroll
    for (int q = 0; q < 4; q++)
#pragma unroll
        for (int x = 0; x < 4; x++) acc[q][x] = 0.f;
    int pr = t >> 4;
    int ph = (t >> 2) & 3;
    int pj0 = (t & 3) * 8;
    const float4* whv = (const float4*)wh;
    for (int jt = 0; jt < JSLICE / 32; jt++) {
        __syncthreads();
        int jb = jbase + jt * 32;
        for (int idx = t; idx < 32 * 64; idx += 256) {
            int jj = idx >> 6, c4 = idx & 63;
            *(float4*)&Whs[jj][c4 * 4] = whv[(size_t)(jb + jj) * 64 + c4];
        }
        if (t < 128) {
            int hh = t >> 5, jj = t & 31;
            dsts[hh][jj] = dstb[hh * 4096 + jb + jj];
        }
        __syncthreads();
        {
            float s_i = ssrc[pr][ph], m_i = sm[pr][ph], inv = sinv[pr][ph];
#pragma unroll
            for (int u = 0; u < 8; u++) {
                int jj = pj0 + u;
                int jl = jt * 32 + jj;
                float e = s_i + dsts[ph][jj];
                e = e > 0.f ? e : 0.2f * e;
                unsigned long long bit = (mb[pr][jl >> 6] >> (jl & 63)) & 1ull;
                float p = __expf(fminf(e - m_i, 0.f)) * inv;
                ps[pr][ph][jj] = bit ? p : 0.f;
            }
        }
        __syncthreads();
#pragma unroll 4
        for (int jj = 0; jj < 32; jj++) {
            float4 wv = *(const float4*)&Whs[jj][cb];
#pragma unroll
            for (int q = 0; q < 4; q++) {
                float p = ps[w * 4 + q][hc][jj];
                acc[q][0] = fmaf(p, wv.x, acc[q][0]);
                acc[q][1] = fmaf(p, wv.y, acc[q][1]);
                acc[q][2] = fmaf(p, wv.z, acc[q][2]);
                acc[q][3] = fmaf(p, wv.w, acc[q][3]);
            }
        }
    }
#pragma unroll
    for (int q = 0; q < 4; q++) {
        int row = i0 + w * 4 + q;
        float* o = hnew + (size_t)row * 256 + cb;
        atomicAdd(o + 0, acc[q][0]); atomicAdd(o + 1, acc[q][1]);
        atomicAdd(o + 2, acc[q][2]); atomicAdd(o + 3, acc[q][3]);
    }
}

// ---------------- h = 0.5*relu(hnew) + 0.5*h -----------------------------------------
__global__ void k_epilogue(const float* hnew, float* h) {
    int idx = blockIdx.x * 256 + threadIdx.x;
    h[idx] = 0.5f * fmaxf(hnew[idx], 0.f) + 0.5f * h[idx];
}

// ---------------- final scores + cos ---------------------------------------------------
__global__ void k_scores(const float* h, float* scoresv, float* cosv) {
    __shared__ float red[12];
    int n = blockIdx.x, t = threadIdx.x;
    int row = 1 + MD + n;
    float qv = h[t], sv = h[(size_t)row * 256 + t];
    float a = qv * qv, b = sv * sv, c = qv * sv;
    for (int o = 32; o > 0; o >>= 1) {
        a += __shfl_down(a, o); b += __shfl_down(b, o); c += __shfl_down(c, o);
    }
    int w = t >> 6;
    if ((t & 63) == 0) { red[w] = a; red[4 + w] = b; red[8 + w] = c; }
    __syncthreads();
    if (t == 0) {
        float qq = red[0] + red[1] + red[2] + red[3];
        float ss = red[4] + red[5] + red[6] + red[7];
        float qs = red[8] + red[9] + red[10] + red[11];
        scoresv[n] = qs * (1.f / 16.f);
        cosv[n] = qs / ((sqrtf(qq) + 1e-8f) * (sqrtf(ss) + 1e-8f));
    }
}

// ---------------- softmax over scores (single block) ----------------------------------
__global__ void k_softmax(const float* scoresv, float* awv) {
    __shared__ float red[4];
    int t = threadIdx.x;
    float m = -__builtin_inff();
    for (int n = t; n < NDOCS; n += 256) m = fmaxf(m, scoresv[n]);
    for (int o = 32; o > 0; o >>= 1) m = fmaxf(m, __shfl_down(m, o));
    if ((t & 63) == 0) red[t >> 6] = m;
    __syncthreads();
    m = fmaxf(fmaxf(red[0], red[1]), fmaxf(red[2], red[3]));
    __syncthreads();
    float s = 0.f;
    for (int n = t; n < NDOCS; n += 256) s += __expf(scoresv[n] - m);
    for (int o = 32; o > 0; o >>= 1) s += __shfl_down(s, o);
    if ((t & 63) == 0) red[t >> 6] = s;
    __syncthreads();
    s = red[0] + red[1] + red[2] + red[3];
    float inv = 1.f / s;
    for (int n = t; n < NDOCS; n += 256) awv[n] = __expf(scoresv[n] - m) * inv;
}

// ---------------- fused feature GEMM + output ----------------------------------------
#define TN 8
__global__ __launch_bounds__(256) void k_fusion(const float* h, const float* awv,
                                                const float* cosv, const float* fwT,
                                                const void* fusion_b, const void* out_w,
                                                const void* out_bp, void* outv,
                                                const int* flagp) {
    __shared__ float feats[TN][516];
    __shared__ float qhs[256];
    __shared__ float red[TN][4];
    int isbf = flagp[0];
    int t = threadIdx.x;
    int n0 = blockIdx.x * TN;
    qhs[t] = h[t];
    __syncthreads();
    for (int idx = t; idx < TN * 514; idx += 256) {
        int r = idx / 514, j = idx % 514;
        int n = n0 + r;
        float v = 0.f;
        if (n < NDOCS) {
            if (j < 256) v = h[(size_t)(1 + MD + n) * 256 + j];
            else if (j < 512) v = qhs[j - 256] * (awv[n] + 0.5f);
            else if (j == 512) v = cosv[n];
            else v = awv[n];
        }
        feats[r][j] = v;
    }
    __syncthreads();
    float acc[TN];
    float bk = ldf(fusion_b, t, isbf);
#pragma unroll
    for (int r = 0; r < TN; r++) acc[r] = bk;
    for (int j = 0; j < 514; j++) {
        float wv = fwT[j * 256 + t];
#pragma unroll
        for (int r = 0; r < TN; r++) acc[r] = fmaf(feats[r][j], wv, acc[r]);
    }
    float ow = ldf(out_w, t, isbf);
    float outb = ldf(out_bp, 0, isbf);
#pragma unroll
    for (int r = 0; r < TN; r++) {
        float o = fmaxf(acc[r], 0.f) * ow;
        for (int off = 32; off > 0; off >>= 1) o += __shfl_down(o, off);
        if ((t & 63) == 0) red[r][t >> 6] = o;
    }
    __syncthreads();
    if (t < TN) {
        int n = n0 + t;
        if (n < NDOCS) {
            float o = red[t][0] + red[t][1] + red[t][2] + red[t][3] + outb + 0.5f * cosv[n];
            if (isbf) ((bf16*)outv)[n] = __float2bfloat16(o);
            else      ((float*)outv)[n] = o;
        }
    }
}

extern "C" void kernel_launch(void* const* d_in, const int* in_sizes, int n_in,
                              void* d_out, int out_size, void* d_ws, size_t ws_size,
                              hipStream_t stream) {
    const void* emb      = d_in[0];
    const int*  adj      = (const int*)d_in[1];
    const void* proj_w   = d_in[3];
    const void* proj_b   = d_in[4];
    const void* ln_scale = d_in[5];
    const void* ln_bias  = d_in[6];
    const void* gat_W    = d_in[7];
    const void* gat_a    = d_in[8];
    const void* fusion_w = d_in[9];
    const void* fusion_b = d_in[10];
    const void* out_w    = d_in[11];
    const void* out_b    = d_in[12];

    unsigned long long* maskb = (unsigned long long*)d_ws;
    int* flag = (int*)((char*)d_ws + (size_t)4096 * 64 * 8);
    float* f = (float*)((char*)d_ws + (size_t)4096 * 64 * 8 + 256);
    float* h       = f; f += 4096 * 256;
    float* wh      = f; f += 4096 * 256;
    float* hnew    = f; f += 4096 * 256;
    float* srcb    = f; f += 4 * 4096;
    float* dstb    = f; f += 4 * 4096;
    float* mrow    = f; f += 4 * 4096;
    float* lrow    = f; f += 4 * 4096;
    float* projT   = f; f += EMB * 256;
    float* gatT    = f; f += 2 * 256 * 256;
    float* fwT     = f; f += 514 * 256;
    float* scoresv = f; f += 4096;
    float* cosv    = f; f += 4096;
    float* awv     = f; f += 4096;

    k_detect<<<dim3(1), dim3(256), 0, stream>>>((const uint16_t*)emb, flag);
    k_transpose<<<dim3(1410), dim3(256), 0, stream>>>(proj_w, gat_W, fusion_w, projT, gatT, fwT, flag);
    k_adjmask<<<dim3(4096), dim3(256), 0, stream>>>(adj, maskb);
    k_proj<<<dim3(TOTAL / PR), dim3(256), 0, stream>>>(emb, proj_b, projT, h, flag);
    k_cosupdate<<<dim3(NDOCS), dim3(256), 0, stream>>>(h);
    for (int layer = 0; layer < 2; layer++) {
        k_ln_wh<<<dim3(TOTAL / LR), dim3(256), 0, stream>>>(h, gatT, ln_scale, ln_bias, gat_a,
                                                            wh, srcb, dstb, layer, flag);
        k_stats<<<dim3(4096), dim3(256), 0, stream>>>(srcb, dstb, maskb, mrow, lrow);
        hipMemsetAsync(hnew, 0, (size_t)4096 * 256 * 4, stream);
        k_pv<<<dim3(TOTAL / TI, JS), dim3(256), 0, stream>>>(wh, srcb, dstb, mrow, lrow, maskb, hnew);
        k_epilogue<<<dim3(4096), dim3(256), 0, stream>>>(hnew, h);
    }
    k_scores<<<dim3(NDOCS), dim3(256), 0, stream>>>(h, scoresv, cosv);
    k_softmax<<<dim3(1), dim3(256), 0, stream>>>(scoresv, awv);
    k_fusion<<<dim3((NDOCS + TN - 1) / TN), dim3(256), 0, stream>>>(h, awv, cosv, fwT,
                                                                    fusion_b, out_w, out_b, flag ? (void*)d_out : (void*)d_out,
                                                                    flag);
}

// Round 3
// 662.864 us; speedup vs baseline: 1.3289x; 1.3289x over previous
//
#include <hip/hip_runtime.h>
#include <hip/hip_bf16.h>
#include <stdint.h>

#define TOTAL 4096
#define EMB 384
#define MD 32
#define NDOCS (TOTAL - 1 - MD)   // 4063
#define LN_EPS 1e-5f

typedef __hip_bfloat16 bf16;
typedef unsigned short ushort_t;
typedef __attribute__((ext_vector_type(8))) short short8;
typedef __attribute__((ext_vector_type(4))) float f32x4;

// Dual-dtype load: inputs may be stored bf16 or fp32; isbf selects at runtime.
__device__ __forceinline__ float ldf(const void* p, int i, int isbf) {
    return isbf ? __bfloat162float(((const bf16*)p)[i]) : ((const float*)p)[i];
}

// round-half-up f32 -> bf16 bits (2 ops; bias <= 0.5 ulp, inputs finite)
__device__ __forceinline__ ushort_t f2bf(float x) {
    return (ushort_t)((__float_as_uint(x) + 0x8000u) >> 16);
}

// ---------------- detect storage dtype of float inputs --------------------------------
__global__ void k_detect(const uint16_t* p, int* flag) {
    __shared__ int red[4];
    int t = threadIdx.x;
    int cnt = 0;
    for (int k = t; k < 4096; k += 256) {
        uint16_t w = p[2 * k];
        int e = (w >> 7) & 0xFF;
        if (e >= 100 && e <= 140) cnt++;
    }
    for (int o = 32; o > 0; o >>= 1) cnt += __shfl_down(cnt, o);
    if ((t & 63) == 0) red[t >> 6] = cnt;
    __syncthreads();
    if (t == 0) flag[0] = (red[0] + red[1] + red[2] + red[3] > 2048) ? 1 : 0;
}

// ---------------- transpose weights (-> fp32, transposed for coalesced reads) ---------
__global__ void k_transpose(const void* proj_w, const void* gat_W, const void* fusion_w,
                            float* projT, float* gatT, float* fwT, const int* flagp) {
    int isbf = flagp[0];
    int idx = blockIdx.x * 256 + threadIdx.x;
    if (idx < EMB * 256) {                      // projT[d*256+c] = proj_w[c*EMB+d]
        int d = idx >> 8, c = idx & 255;
        projT[idx] = ldf(proj_w, c * EMB + d, isbf);
    } else if (idx < EMB * 256 + 2 * 256 * 256) {
        int r = idx - EMB * 256;
        int l = r >> 16; int rem = r & 65535;
        int d = rem >> 8, c = rem & 255;        // gatT[l][d*256+c] = gat_W[l][c*256+d]
        gatT[r] = ldf(gat_W, l * 65536 + c * 256 + d, isbf);
    } else if (idx < EMB * 256 + 2 * 256 * 256 + 514 * 256) {
        int r = idx - (EMB * 256 + 2 * 256 * 256);
        int j = r >> 8, c = r & 255;            // fwT[j*256+c] = fusion_w[c*514+j]
        fwT[r] = ldf(fusion_w, c * 514 + j, isbf);
    }
}

// ---------------- adj -> per-row bitmask (bit set = edge present) --------------------
__global__ void k_adjmask(const int* adj, unsigned long long* maskb) {
    int i = blockIdx.x;
    int t = threadIdx.x;
    int w = t >> 6, l = t & 63;
    for (int c = w; c < 64; c += 4) {
        int a = adj[(size_t)i * TOTAL + c * 64 + l];
        unsigned long long m = __ballot(a != 0);
        if (l == 0) maskb[i * 64 + c] = m;
    }
}

// ---------------- h = relu(emb @ projT + b), 8 rows/block -----------------------------
#define PR 8
__global__ void k_proj(const void* emb, const void* proj_b, const float* projT, float* h,
                       const int* flagp) {
    __shared__ float xs[PR][EMB];
    int isbf = flagp[0];
    int i0 = blockIdx.x * PR, t = threadIdx.x;
    for (int idx = t; idx < PR * EMB; idx += 256) {
        int r = idx / EMB, d = idx % EMB;
        xs[r][d] = ldf(emb, (i0 + r) * EMB + d, isbf);
    }
    __syncthreads();
    float acc[PR];
    float bias = ldf(proj_b, t, isbf);
#pragma unroll
    for (int r = 0; r < PR; r++) acc[r] = bias;
    for (int d = 0; d < EMB; d++) {
        float wv = projT[d * 256 + t];
#pragma unroll
        for (int r = 0; r < PR; r++) acc[r] = fmaf(xs[r][d], wv, acc[r]);
    }
#pragma unroll
    for (int r = 0; r < PR; r++) h[(size_t)(i0 + r) * 256 + t] = fmaxf(acc[r], 0.f);
}

// ---------------- query-aware doc update: s += 0.8*cos(q,s)*q (grid-stride) ----------
__global__ void k_cosupdate(float* h) {
    __shared__ float red[8];
    __shared__ float qqs;
    int t = threadIdx.x, w = t >> 6;
    float qv = h[t];
    float a = qv * qv;
    for (int o = 32; o > 0; o >>= 1) a += __shfl_down(a, o);
    if ((t & 63) == 0) red[w] = a;
    __syncthreads();
    if (t == 0) qqs = red[0] + red[1] + red[2] + red[3];
    __syncthreads();
    float qq = qqs;
    for (int n = blockIdx.x; n < NDOCS; n += 128) {
        size_t row = (size_t)(1 + MD + n) * 256;
        float sv = h[row + t];
        float b = sv * sv, c = qv * sv;
        for (int o = 32; o > 0; o >>= 1) { b += __shfl_down(b, o); c += __shfl_down(c, o); }
        __syncthreads();
        if ((t & 63) == 0) { red[w] = b; red[4 + w] = c; }
        __syncthreads();
        float ss = red[0] + red[1] + red[2] + red[3];
        float qs = red[4] + red[5] + red[6] + red[7];
        float cosv = qs / ((sqrtf(qq) + 1e-8f) * (sqrtf(ss) + 1e-8f));
        h[row + t] = sv + 0.8f * cosv * qv;
    }
}

// ---------------- layernorm + Wh GEMM + src/dst; Wh emitted bf16 B-frag-swizzled ------
// whswz layout (ushort): [jtile=j>>5][ct=c>>4][q=(j>>3)&3][c16=c&15][u=j&7]
// so k_pv's lane (quad,c16) reads its 8 contiguous k-elements with one ds_read_b128.
#define LR 4
__global__ void k_ln_wh(const float* h, const float* gatT, const void* ln_scale,
                        const void* ln_bias, const void* gat_a,
                        ushort_t* whswz, float* srcb, float* dstb, int layer, const int* flagp) {
    __shared__ float xs[LR][256];
    __shared__ float red[2][LR][4];
    int isbf = flagp[0];
    int i0 = blockIdx.x * LR, t = threadIdx.x;
    int w = t >> 6, l = t & 63;
    float scale = ldf(ln_scale, layer * 256 + t, isbf);
    float bias = ldf(ln_bias, layer * 256 + t, isbf);
    float hv[LR];
#pragma unroll
    for (int r = 0; r < LR; r++) hv[r] = h[(size_t)(i0 + r) * 256 + t];
#pragma unroll
    for (int r = 0; r < LR; r++) {
        float a = hv[r], b = hv[r] * hv[r];
        for (int o = 32; o > 0; o >>= 1) { a += __shfl_down(a, o); b += __shfl_down(b, o); }
        if (l == 0) { red[0][r][w] = a; red[1][r][w] = b; }
    }
    __syncthreads();
#pragma unroll
    for (int r = 0; r < LR; r++) {
        float mu = (red[0][r][0] + red[0][r][1] + red[0][r][2] + red[0][r][3]) * (1.f / 256.f);
        float var = (red[1][r][0] + red[1][r][1] + red[1][r][2] + red[1][r][3]) * (1.f / 256.f) - mu * mu;
        float x = (hv[r] - mu) * rsqrtf(var + LN_EPS) * scale + bias;
        xs[r][t] = x;
    }
    __syncthreads();
    const float* gT = gatT + layer * 65536;
    float acc[LR] = {0.f, 0.f, 0.f, 0.f};
    for (int d = 0; d < 256; d++) {
        float wv = gT[d * 256 + t];
#pragma unroll
        for (int r = 0; r < LR; r++) acc[r] = fmaf(xs[r][d], wv, acc[r]);
    }
    float av1 = ldf(gat_a, layer * 512 + w * 128 + l, isbf);
    float av2 = ldf(gat_a, layer * 512 + w * 128 + 64 + l, isbf);
    int ct = t >> 4, c16 = t & 15;
#pragma unroll
    for (int r = 0; r < LR; r++) {
        int i = i0 + r;
        int off = (i >> 5) * 8192 + ct * 512 + ((i >> 3) & 3) * 128 + c16 * 8 + (i & 7);
        whswz[off] = f2bf(acc[r]);
        float sv = acc[r] * av1, dv = acc[r] * av2;
        for (int o = 32; o > 0; o >>= 1) { sv += __shfl_down(sv, o); dv += __shfl_down(dv, o); }
        if (l == 0) { srcb[w * 4096 + i0 + r] = sv; dstb[w * 4096 + i0 + r] = dv; }
    }
}

// ---------------- online softmax stats per (row, head): m and 1/l ---------------------
__global__ void k_stats(const float* srcb, const float* dstb, const unsigned long long* maskb,
                        float* mrow, float* lrow) {
    __shared__ unsigned long long mb[64];
    int i = blockIdx.x, t = threadIdx.x;
    if (t < 64) mb[t] = maskb[i * 64 + t];
    __syncthreads();
    int w = t >> 6, l = t & 63;
    float si = srcb[w * 4096 + i];
    const float* dp = dstb + w * 4096;
    float m = -__builtin_inff(), s = 0.f;
    for (int c = 0; c < 64; c++) {
        float e = si + dp[c * 64 + l];
        e = e > 0.f ? e : 0.2f * e;
        if ((mb[c] >> l) & 1ull) {
            float M = fmaxf(m, e);
            s = s * __expf(fminf(m - M, 0.f)) + __expf(e - M);
            m = M;
        }
    }
    for (int o = 1; o < 64; o <<= 1) {
        float m2 = __shfl_xor(m, o), s2 = __shfl_xor(s, o);
        float M = fmaxf(m, m2);
        s = s * __expf(fminf(m - M, 0.f)) + s2 * __expf(fminf(m2 - M, 0.f));
        m = M;
    }
    if (l == 0) { mrow[w * 4096 + i] = m; lrow[w * 4096 + i] = 1.f / s; }
}

// ---------------- PV via MFMA: hn[i,c] = sum_j p(i,h(c),j) * Wh[j,c] ------------------
// Block: 512 thr = 8 waves = 4 heads x 2 K-halves; 16 query rows per block.
// Lane computes its A-frag of P directly in MFMA A-layout (row=lane&15, k=quad*8+u).
// B-frags read from LDS-staged whswz (bf16, pre-swizzled). K-halves summed via LDS.
__global__ __launch_bounds__(512) void k_pv(const ushort_t* whswz, const float* srcb,
                                            const float* dstb, const float* mrow,
                                            const float* lrow,
                                            const unsigned long long* maskb, float* hnew) {
    __shared__ ushort_t Bs[2][8192];                 // 32 KB: [khalf][ct*512+q*128+c16*8+u]
    __shared__ unsigned long long mbs[16][65];       // padded: conflict-free per-row reads
    __shared__ float dsts[2][4][32];
    __shared__ float srcs[4][16], rces[4][16];
    __shared__ f32x4 accx[4][4][64];                 // cross-K-half reduction
    int t = threadIdx.x;
    int W = t >> 6, lane = t & 63;
    int h = W & 3, ks2 = W >> 2;
    int quad = lane >> 4, c16 = lane & 15;
    int i0 = blockIdx.x * 16;
    for (int idx = t; idx < 16 * 64; idx += 512) {
        int r = idx >> 6, wd = idx & 63;
        mbs[r][wd] = maskb[(size_t)(i0 + r) * 64 + wd];
    }
    if (t < 64) {
        int h2 = t >> 4, r = t & 15;
        srcs[h2][r] = srcb[h2 * 4096 + i0 + r];
        float m = mrow[h2 * 4096 + i0 + r];
        float inv = lrow[h2 * 4096 + i0 + r];
        rces[h2][r] = __logf(inv) - m;               // p = exp(lrelu(e) + rce)
    }
    __syncthreads();
    float src_i = srcs[h][c16];
    float rce_i = rces[h][c16];
    f32x4 acc[4];
#pragma unroll
    for (int ct = 0; ct < 4; ct++) acc[ct] = (f32x4){0.f, 0.f, 0.f, 0.f};
    const uint4* g4 = (const uint4*)whswz;
    for (int step = 0; step < 64; step++) {
        __syncthreads();
        for (int idx = t; idx < 2048; idx += 512) {  // stage both 16KB B-tiles
            int hsel = idx >> 10, sub = idx & 1023;
            ((uint4*)Bs)[idx] = g4[(size_t)(hsel * 64 + step) * 1024 + sub];
        }
        if (t < 256) {
            int hsel = t >> 7, hh = (t >> 5) & 3, jj = t & 31;
            dsts[hsel][hh][jj] = dstb[hh * 4096 + hsel * 2048 + step * 32 + jj];
        }
        __syncthreads();
        int koff = ks2 * 2048 + step * 32 + quad * 8;
        unsigned long long mw = mbs[c16][koff >> 6];
        unsigned int mbyte = (unsigned int)(mw >> (koff & 63)) & 0xFFu;
        const float* dp = &dsts[ks2][h][quad * 8];
        float4 d0 = *(const float4*)dp;
        float4 d1 = *(const float4*)(dp + 4);
        float dj[8] = {d0.x, d0.y, d0.z, d0.w, d1.x, d1.y, d1.z, d1.w};
        short8 af;
#pragma unroll
        for (int u = 0; u < 8; u++) {
            float e = src_i + dj[u];
            float lrv = fmaxf(e, 0.2f * e);          // leaky_relu, branchless
            float p = __expf(lrv + rce_i);
            p = ((mbyte >> u) & 1u) ? p : 0.f;
            af[u] = (short)f2bf(p);
        }
        const ushort_t* bbase = &Bs[ks2][h * 2048 + quad * 128 + c16 * 8];
#pragma unroll
        for (int ct = 0; ct < 4; ct++) {
            short8 bf = *(const short8*)(bbase + ct * 512);
            acc[ct] = __builtin_amdgcn_mfma_f32_16x16x32_bf16(af, bf, acc[ct], 0, 0, 0);
        }
    }
    if (ks2 == 1) {
#pragma unroll
        for (int ct = 0; ct < 4; ct++) accx[h][ct][lane] = acc[ct];
    }
    __syncthreads();
    if (ks2 == 0) {
#pragma unroll
        for (int ct = 0; ct < 4; ct++) {
            f32x4 o = acc[ct] + accx[h][ct][lane];
#pragma unroll
            for (int r = 0; r < 4; r++) {            // D: col=lane&15, row=quad*4+r
                int row = i0 + quad * 4 + r;
                hnew[(size_t)row * 256 + h * 64 + ct * 16 + c16] = o[r];
            }
        }
    }
}

// ---------------- h = 0.5*relu(hnew) + 0.5*h (float4) ---------------------------------
__global__ void k_epilogue(const float* hnew, float* h) {
    int idx = blockIdx.x * 256 + threadIdx.x;
    const float4* n4 = (const float4*)hnew;
    float4* h4 = (float4*)h;
    float4 n = n4[idx], hh = h4[idx];
    hh.x = 0.5f * fmaxf(n.x, 0.f) + 0.5f * hh.x;
    hh.y = 0.5f * fmaxf(n.y, 0.f) + 0.5f * hh.y;
    hh.z = 0.5f * fmaxf(n.z, 0.f) + 0.5f * hh.z;
    hh.w = 0.5f * fmaxf(n.w, 0.f) + 0.5f * hh.w;
    h4[idx] = hh;
}

// ---------------- final scores + cos ---------------------------------------------------
__global__ void k_scores(const float* h, float* scoresv, float* cosv) {
    __shared__ float red[12];
    int n = blockIdx.x, t = threadIdx.x;
    int row = 1 + MD + n;
    float qv = h[t], sv = h[(size_t)row * 256 + t];
    float a = qv * qv, b = sv * sv, c = qv * sv;
    for (int o = 32; o > 0; o >>= 1) {
        a += __shfl_down(a, o); b += __shfl_down(b, o); c += __shfl_down(c, o);
    }
    int w = t >> 6;
    if ((t & 63) == 0) { red[w] = a; red[4 + w] = b; red[8 + w] = c; }
    __syncthreads();
    if (t == 0) {
        float qq = red[0] + red[1] + red[2] + red[3];
        float ss = red[4] + red[5] + red[6] + red[7];
        float qs = red[8] + red[9] + red[10] + red[11];
        scoresv[n] = qs * (1.f / 16.f);
        cosv[n] = qs / ((sqrtf(qq) + 1e-8f) * (sqrtf(ss) + 1e-8f));
    }
}

// ---------------- softmax over scores (single block) ----------------------------------
__global__ void k_softmax(const float* scoresv, float* awv) {
    __shared__ float red[4];
    int t = threadIdx.x;
    float m = -__builtin_inff();
    for (int n = t; n < NDOCS; n += 256) m = fmaxf(m, scoresv[n]);
    for (int o = 32; o > 0; o >>= 1) m = fmaxf(m, __shfl_down(m, o));
    if ((t & 63) == 0) red[t >> 6] = m;
    __syncthreads();
    m = fmaxf(fmaxf(red[0], red[1]), fmaxf(red[2], red[3]));
    __syncthreads();
    float s = 0.f;
    for (int n = t; n < NDOCS; n += 256) s += __expf(scoresv[n] - m);
    for (int o = 32; o > 0; o >>= 1) s += __shfl_down(s, o);
    if ((t & 63) == 0) red[t >> 6] = s;
    __syncthreads();
    s = red[0] + red[1] + red[2] + red[3];
    float inv = 1.f / s;
    for (int n = t; n < NDOCS; n += 256) awv[n] = __expf(scoresv[n] - m) * inv;
}

// ---------------- fused feature GEMM + output ----------------------------------------
#define TN 8
__global__ __launch_bounds__(256) void k_fusion(const float* h, const float* awv,
                                                const float* cosv, const float* fwT,
                                                const void* fusion_b, const void* out_w,
                                                const void* out_bp, void* outv,
                                                const int* flagp) {
    __shared__ float feats[TN][516];
    __shared__ float qhs[256];
    __shared__ float red[TN][4];
    int isbf = flagp[0];
    int t = threadIdx.x;
    int n0 = blockIdx.x * TN;
    qhs[t] = h[t];
    __syncthreads();
    for (int idx = t; idx < TN * 514; idx += 256) {
        int r = idx / 514, j = idx % 514;
        int n = n0 + r;
        float v = 0.f;
        if (n < NDOCS) {
            if (j < 256) v = h[(size_t)(1 + MD + n) * 256 + j];
            else if (j < 512) v = qhs[j - 256] * (awv[n] + 0.5f);
            else if (j == 512) v = cosv[n];
            else v = awv[n];
        }
        feats[r][j] = v;
    }
    __syncthreads();
    float acc[TN];
    float bk = ldf(fusion_b, t, isbf);
#pragma unroll
    for (int r = 0; r < TN; r++) acc[r] = bk;
    for (int j = 0; j < 514; j++) {
        float wv = fwT[j * 256 + t];
#pragma unroll
        for (int r = 0; r < TN; r++) acc[r] = fmaf(feats[r][j], wv, acc[r]);
    }
    float ow = ldf(out_w, t, isbf);
    float outb = ldf(out_bp, 0, isbf);
#pragma unroll
    for (int r = 0; r < TN; r++) {
        float o = fmaxf(acc[r], 0.f) * ow;
        for (int off = 32; off > 0; off >>= 1) o += __shfl_down(o, off);
        if ((t & 63) == 0) red[r][t >> 6] = o;
    }
    __syncthreads();
    if (t < TN) {
        int n = n0 + t;
        if (n < NDOCS) {
            float o = red[t][0] + red[t][1] + red[t][2] + red[t][3] + outb + 0.5f * cosv[n];
            if (isbf) ((bf16*)outv)[n] = __float2bfloat16(o);
            else      ((float*)outv)[n] = o;
        }
    }
}

extern "C" void kernel_launch(void* const* d_in, const int* in_sizes, int n_in,
                              void* d_out, int out_size, void* d_ws, size_t ws_size,
                              hipStream_t stream) {
    const void* emb      = d_in[0];
    const int*  adj      = (const int*)d_in[1];
    const void* proj_w   = d_in[3];
    const void* proj_b   = d_in[4];
    const void* ln_scale = d_in[5];
    const void* ln_bias  = d_in[6];
    const void* gat_W    = d_in[7];
    const void* gat_a    = d_in[8];
    const void* fusion_w = d_in[9];
    const void* fusion_b = d_in[10];
    const void* out_w    = d_in[11];
    const void* out_b    = d_in[12];

    unsigned long long* maskb = (unsigned long long*)d_ws;
    int* flag = (int*)((char*)d_ws + (size_t)4096 * 64 * 8);
    float* f = (float*)((char*)d_ws + (size_t)4096 * 64 * 8 + 256);
    float* h       = f; f += 4096 * 256;
    float* hnew    = f; f += 4096 * 256;
    float* srcb    = f; f += 4 * 4096;
    float* dstb    = f; f += 4 * 4096;
    float* mrow    = f; f += 4 * 4096;
    float* lrow    = f; f += 4 * 4096;
    float* projT   = f; f += EMB * 256;
    float* gatT    = f; f += 2 * 256 * 256;
    float* fwT     = f; f += 514 * 256;
    float* scoresv = f; f += 4096;
    float* cosv    = f; f += 4096;
    float* awv     = f; f += 4096;
    ushort_t* whswz = (ushort_t*)f;   // 4096*256 ushorts = 2MB

    k_detect<<<dim3(1), dim3(256), 0, stream>>>((const uint16_t*)emb, flag);
    k_transpose<<<dim3(1410), dim3(256), 0, stream>>>(proj_w, gat_W, fusion_w, projT, gatT, fwT, flag);
    k_adjmask<<<dim3(4096), dim3(256), 0, stream>>>(adj, maskb);
    k_proj<<<dim3(TOTAL / PR), dim3(256), 0, stream>>>(emb, proj_b, projT, h, flag);
    k_cosupdate<<<dim3(128), dim3(256), 0, stream>>>(h);
    for (int layer = 0; layer < 2; layer++) {
        k_ln_wh<<<dim3(TOTAL / LR), dim3(256), 0, stream>>>(h, gatT, ln_scale, ln_bias, gat_a,
                                                            whswz, srcb, dstb, layer, flag);
        k_stats<<<dim3(4096), dim3(256), 0, stream>>>(srcb, dstb, maskb, mrow, lrow);
        k_pv<<<dim3(256), dim3(512), 0, stream>>>(whswz, srcb, dstb, mrow, lrow, maskb, hnew);
        k_epilogue<<<dim3(1024), dim3(256), 0, stream>>>(hnew, h);
    }
    k_scores<<<dim3(NDOCS), dim3(256), 0, stream>>>(h, scoresv, cosv);
    k_softmax<<<dim3(1), dim3(256), 0, stream>>>(scoresv, awv);
    k_fusion<<<dim3((NDOCS + TN - 1) / TN), dim3(256), 0, stream>>>(h, awv, cosv, fwT,
                                                                    fusion_b, out_w, out_b,
                                                                    (void*)d_out, flag);
}

// Round 4
// 456.089 us; speedup vs baseline: 1.9314x; 1.4534x over previous
//
#include <hip/hip_runtime.h>
#include <hip/hip_bf16.h>
#include <stdint.h>

#define TOTAL 4096
#define EMB 384
#define MD 32
#define NDOCS (TOTAL - 1 - MD)   // 4063
#define LN_EPS 1e-5f

typedef __hip_bfloat16 bf16;
typedef unsigned short ushort_t;
typedef __attribute__((ext_vector_type(8))) short short8;
typedef __attribute__((ext_vector_type(4))) float f32x4;

// Dual-dtype load: inputs may be stored bf16 or fp32; isbf selects at runtime.
__device__ __forceinline__ float ldf(const void* p, int i, int isbf) {
    return isbf ? __bfloat162float(((const bf16*)p)[i]) : ((const float*)p)[i];
}

// round-half-up f32 -> bf16 bits (2 ops; bias <= 0.5 ulp, inputs finite)
__device__ __forceinline__ ushort_t f2bf(float x) {
    return (ushort_t)((__float_as_uint(x) + 0x8000u) >> 16);
}

// ---------------- detect storage dtype of float inputs --------------------------------
__global__ void k_detect(const uint16_t* p, int* flag) {
    __shared__ int red[4];
    int t = threadIdx.x;
    int cnt = 0;
    for (int k = t; k < 4096; k += 256) {
        uint16_t w = p[2 * k];
        int e = (w >> 7) & 0xFF;
        if (e >= 100 && e <= 140) cnt++;
    }
    for (int o = 32; o > 0; o >>= 1) cnt += __shfl_down(cnt, o);
    if ((t & 63) == 0) red[t >> 6] = cnt;
    __syncthreads();
    if (t == 0) flag[0] = (red[0] + red[1] + red[2] + red[3] > 2048) ? 1 : 0;
}

// ---------------- transpose weights (-> fp32, transposed for coalesced reads) ---------
__global__ void k_transpose(const void* proj_w, const void* gat_W, const void* fusion_w,
                            float* projT, float* gatT, float* fwT, const int* flagp) {
    int isbf = flagp[0];
    int idx = blockIdx.x * 256 + threadIdx.x;
    if (idx < EMB * 256) {                      // projT[d*256+c] = proj_w[c*EMB+d]
        int d = idx >> 8, c = idx & 255;
        projT[idx] = ldf(proj_w, c * EMB + d, isbf);
    } else if (idx < EMB * 256 + 2 * 256 * 256) {
        int r = idx - EMB * 256;
        int l = r >> 16; int rem = r & 65535;
        int d = rem >> 8, c = rem & 255;        // gatT[l][d*256+c] = gat_W[l][c*256+d]
        gatT[r] = ldf(gat_W, l * 65536 + c * 256 + d, isbf);
    } else if (idx < EMB * 256 + 2 * 256 * 256 + 514 * 256) {
        int r = idx - (EMB * 256 + 2 * 256 * 256);
        int j = r >> 8, c = r & 255;            // fwT[j*256+c] = fusion_w[c*514+j]
        fwT[r] = ldf(fusion_w, c * 514 + j, isbf);
    }
}

// ---------------- adj -> per-row bitmask (bit set = edge present) --------------------
__global__ void k_adjmask(const int* adj, unsigned long long* maskb) {
    int i = blockIdx.x;
    int t = threadIdx.x;
    int w = t >> 6, l = t & 63;
    for (int c = w; c < 64; c += 4) {
        int a = adj[(size_t)i * TOTAL + c * 64 + l];
        unsigned long long m = __ballot(a != 0);
        if (l == 0) maskb[i * 64 + c] = m;
    }
}

// ---------------- h = relu(emb @ projT + b), 8 rows/block -----------------------------
#define PR 8
__global__ void k_proj(const void* emb, const void* proj_b, const float* projT, float* h,
                       const int* flagp) {
    __shared__ float xs[PR][EMB];
    int isbf = flagp[0];
    int i0 = blockIdx.x * PR, t = threadIdx.x;
    for (int idx = t; idx < PR * EMB; idx += 256) {
        int r = idx / EMB, d = idx % EMB;
        xs[r][d] = ldf(emb, (i0 + r) * EMB + d, isbf);
    }
    __syncthreads();
    float acc[PR];
    float bias = ldf(proj_b, t, isbf);
#pragma unroll
    for (int r = 0; r < PR; r++) acc[r] = bias;
    for (int d = 0; d < EMB; d++) {
        float wv = projT[d * 256 + t];
#pragma unroll
        for (int r = 0; r < PR; r++) acc[r] = fmaf(xs[r][d], wv, acc[r]);
    }
#pragma unroll
    for (int r = 0; r < PR; r++) h[(size_t)(i0 + r) * 256 + t] = fmaxf(acc[r], 0.f);
}

// ---------------- query-aware doc update: s += 0.8*cos(q,s)*q (grid-stride) ----------
__global__ void k_cosupdate(float* h) {
    __shared__ float red[8];
    __shared__ float qqs;
    int t = threadIdx.x, w = t >> 6;
    float qv = h[t];
    float a = qv * qv;
    for (int o = 32; o > 0; o >>= 1) a += __shfl_down(a, o);
    if ((t & 63) == 0) red[w] = a;
    __syncthreads();
    if (t == 0) qqs = red[0] + red[1] + red[2] + red[3];
    __syncthreads();
    float qq = qqs;
    for (int n = blockIdx.x; n < NDOCS; n += 128) {
        size_t row = (size_t)(1 + MD + n) * 256;
        float sv = h[row + t];
        float b = sv * sv, c = qv * sv;
        for (int o = 32; o > 0; o >>= 1) { b += __shfl_down(b, o); c += __shfl_down(c, o); }
        __syncthreads();
        if ((t & 63) == 0) { red[w] = b; red[4 + w] = c; }
        __syncthreads();
        float ss = red[0] + red[1] + red[2] + red[3];
        float qs = red[4] + red[5] + red[6] + red[7];
        float cosv = qs / ((sqrtf(qq) + 1e-8f) * (sqrtf(ss) + 1e-8f));
        h[row + t] = sv + 0.8f * cosv * qv;
    }
}

// ---------------- layernorm + Wh GEMM + src/dst; Wh emitted bf16 B-frag-swizzled ------
// whswz (ushort): off = (j>>6)*16384 + (c>>6)*4096 + ((j>>3)&7)*512 + ((c>>4)&3)*128
//                       + (c&15)*8 + (j&7)
// -> each k_pv lane's 16B B-fragment is CONTIGUOUS IN GLOBAL MEMORY (no LDS staging).
// dpre[h][j] = (dst*log2e, 0.2*dst*log2e) pairs for fused exp2 p-compute.
#define LR 4
__global__ void k_ln_wh(const float* h, const float* gatT, const void* ln_scale,
                        const void* ln_bias, const void* gat_a,
                        ushort_t* whswz, float* srcb, float* dstb, float2* dpre,
                        int layer, const int* flagp) {
    __shared__ float xs[LR][256];
    __shared__ float red[2][LR][4];
    int isbf = flagp[0];
    int i0 = blockIdx.x * LR, t = threadIdx.x;
    int w = t >> 6, l = t & 63;
    float scale = ldf(ln_scale, layer * 256 + t, isbf);
    float bias = ldf(ln_bias, layer * 256 + t, isbf);
    float hv[LR];
#pragma unroll
    for (int r = 0; r < LR; r++) hv[r] = h[(size_t)(i0 + r) * 256 + t];
#pragma unroll
    for (int r = 0; r < LR; r++) {
        float a = hv[r], b = hv[r] * hv[r];
        for (int o = 32; o > 0; o >>= 1) { a += __shfl_down(a, o); b += __shfl_down(b, o); }
        if (l == 0) { red[0][r][w] = a; red[1][r][w] = b; }
    }
    __syncthreads();
#pragma unroll
    for (int r = 0; r < LR; r++) {
        float mu = (red[0][r][0] + red[0][r][1] + red[0][r][2] + red[0][r][3]) * (1.f / 256.f);
        float var = (red[1][r][0] + red[1][r][1] + red[1][r][2] + red[1][r][3]) * (1.f / 256.f) - mu * mu;
        float x = (hv[r] - mu) * rsqrtf(var + LN_EPS) * scale + bias;
        xs[r][t] = x;
    }
    __syncthreads();
    const float* gT = gatT + layer * 65536;
    float acc[LR] = {0.f, 0.f, 0.f, 0.f};
    for (int d = 0; d < 256; d++) {
        float wv = gT[d * 256 + t];
#pragma unroll
        for (int r = 0; r < LR; r++) acc[r] = fmaf(xs[r][d], wv, acc[r]);
    }
    float av1 = ldf(gat_a, layer * 512 + w * 128 + l, isbf);
    float av2 = ldf(gat_a, layer * 512 + w * 128 + 64 + l, isbf);
    const float LOG2E = 1.44269504f;
#pragma unroll
    for (int r = 0; r < LR; r++) {
        int i = i0 + r;
        int off = (i >> 6) * 16384 + (t >> 6) * 4096 + ((i >> 3) & 7) * 512 +
                  ((t >> 4) & 3) * 128 + (t & 15) * 8 + (i & 7);
        whswz[off] = f2bf(acc[r]);
        float sv = acc[r] * av1, dv = acc[r] * av2;
        for (int o = 32; o > 0; o >>= 1) { sv += __shfl_down(sv, o); dv += __shfl_down(dv, o); }
        if (l == 0) {
            srcb[w * 4096 + i] = sv;
            dstb[w * 4096 + i] = dv;
            dpre[w * 4096 + i] = make_float2(dv * LOG2E, 0.2f * dv * LOG2E);
        }
    }
}

// ---------------- online softmax stats per (row, head): m and 1/l ---------------------
__global__ void k_stats(const float* srcb, const float* dstb, const unsigned long long* maskb,
                        float* mrow, float* lrow) {
    __shared__ unsigned long long mb[64];
    int i = blockIdx.x, t = threadIdx.x;
    if (t < 64) mb[t] = maskb[i * 64 + t];
    __syncthreads();
    int w = t >> 6, l = t & 63;
    float si = srcb[w * 4096 + i];
    const float* dp = dstb + w * 4096;
    float m = -__builtin_inff(), s = 0.f;
    for (int c = 0; c < 64; c++) {
        float e = si + dp[c * 64 + l];
        e = e > 0.f ? e : 0.2f * e;
        if ((mb[c] >> l) & 1ull) {
            float M = fmaxf(m, e);
            s = s * __expf(fminf(m - M, 0.f)) + __expf(e - M);
            m = M;
        }
    }
    for (int o = 1; o < 64; o <<= 1) {
        float m2 = __shfl_xor(m, o), s2 = __shfl_xor(s, o);
        float M = fmaxf(m, m2);
        s = s * __expf(fminf(m - M, 0.f)) + s2 * __expf(fminf(m2 - M, 0.f));
        m = M;
    }
    if (l == 0) { mrow[w * 4096 + i] = m; lrow[w * 4096 + i] = 1.f / s; }
}

// ---------------- PV via MFMA, barrier-free K-loop ------------------------------------
// Grid: (128 i-tiles of 32 rows) x (4 j-splits of 1024). Block: 512 thr = 8 waves
// = 4 heads x 2 k-quarters. Each wave register-prefetches its own contiguous B-frags
// from global (no LDS staging, no in-loop barriers). p = exp2(max(s1+d1[j], s2+d2[j])).
#define TI 32
#define JS 4
__global__ __launch_bounds__(512) void k_pv(const ushort_t* whswz, const float* srcb,
                                            const float* mrow, const float* lrow,
                                            const float2* dpre,
                                            const unsigned long long* maskb, float* hnp) {
    __shared__ unsigned long long mbs[TI][17];
    __shared__ float2 dpres[4][1024];            // 32KB; aliased by accsh after the loop
    __shared__ float srcs[4][TI], rces[4][TI];
    f32x4* accsh = (f32x4*)dpres;
    int t = threadIdx.x;
    int W = t >> 6, lane = t & 63;
    int h = W & 3, kq = W >> 2;
    int quad = lane >> 4, c16 = lane & 15;
    int i0 = blockIdx.x * TI;
    int jbase = blockIdx.y * 1024;
    for (int idx = t; idx < TI * 16; idx += 512) {
        int r = idx >> 4, wd = idx & 15;
        mbs[r][wd] = maskb[(size_t)(i0 + r) * 64 + (jbase >> 6) + wd];
    }
    for (int idx = t; idx < 4096; idx += 512) {
        int hh = idx >> 10, jl = idx & 1023;
        dpres[hh][jl] = dpre[hh * 4096 + jbase + jl];
    }
    if (t < 128) {
        int h2 = t >> 5, r = t & 31;
        srcs[h2][r] = srcb[h2 * 4096 + i0 + r];
        rces[h2][r] = __logf(lrow[h2 * 4096 + i0 + r]) - mrow[h2 * 4096 + i0 + r];
    }
    __syncthreads();
    const float LOG2E = 1.44269504f;
    float s1[2], s2[2];
#pragma unroll
    for (int rt = 0; rt < 2; rt++) {
        float src = srcs[h][rt * 16 + c16], rce = rces[h][rt * 16 + c16];
        s1[rt] = (src + rce) * LOG2E;
        s2[rt] = (0.2f * src + rce) * LOG2E;
    }
    f32x4 acc[2][4];
#pragma unroll
    for (int rt = 0; rt < 2; rt++)
#pragma unroll
        for (int ct = 0; ct < 4; ct++) acc[rt][ct] = (f32x4){0.f, 0.f, 0.f, 0.f};
    const uint4* g4 = (const uint4*)whswz;
    size_t b0 = (size_t)(jbase >> 6) * 2048 + h * 512 + (kq * 4 + quad) * 64 + c16;
    uint4 bn[4];
#pragma unroll
    for (int ct = 0; ct < 4; ct++) bn[ct] = g4[b0 + ct * 16];
    for (int step = 0; step < 16; step++) {
        uint4 bc[4];
#pragma unroll
        for (int ct = 0; ct < 4; ct++) bc[ct] = bn[ct];
        if (step < 15) {
            size_t bs = b0 + (size_t)(step + 1) * 2048;
#pragma unroll
            for (int ct = 0; ct < 4; ct++) bn[ct] = g4[bs + ct * 16];
        }
        int jl0 = step * 64 + kq * 32 + quad * 8;
        unsigned int mby[2];
#pragma unroll
        for (int rt = 0; rt < 2; rt++)
            mby[rt] = (unsigned int)(mbs[rt * 16 + c16][step] >> (kq * 32 + quad * 8)) & 0xFFu;
        const float4* dp4 = (const float4*)&dpres[h][jl0];
        float4 dv[4];
#pragma unroll
        for (int q = 0; q < 4; q++) dv[q] = dp4[q];
        short8 af[2];
#pragma unroll
        for (int rt = 0; rt < 2; rt++) {
#pragma unroll
            for (int q = 0; q < 4; q++) {
                float4 d = dv[q];
                float pa = exp2f(fmaxf(s1[rt] + d.x, s2[rt] + d.y));
                float pb = exp2f(fmaxf(s1[rt] + d.z, s2[rt] + d.w));
                pa = ((mby[rt] >> (2 * q)) & 1u) ? pa : 0.f;
                pb = ((mby[rt] >> (2 * q + 1)) & 1u) ? pb : 0.f;
                af[rt][2 * q] = (short)f2bf(pa);
                af[rt][2 * q + 1] = (short)f2bf(pb);
            }
        }
#pragma unroll
        for (int ct = 0; ct < 4; ct++) {
            short8 bf = __builtin_bit_cast(short8, bc[ct]);
            acc[0][ct] = __builtin_amdgcn_mfma_f32_16x16x32_bf16(af[0], bf, acc[0][ct], 0, 0, 0);
            acc[1][ct] = __builtin_amdgcn_mfma_f32_16x16x32_bf16(af[1], bf, acc[1][ct], 0, 0, 0);
        }
    }
    __syncthreads();                              // dpres dead; reuse as accsh
    if (kq == 1) {
#pragma unroll
        for (int rt = 0; rt < 2; rt++)
#pragma unroll
            for (int ct = 0; ct < 4; ct++)
                accsh[((h * 2 + rt) * 4 + ct) * 64 + lane] = acc[rt][ct];
    }
    __syncthreads();
    if (kq == 0) {
        float* out = hnp + (size_t)blockIdx.y * (TOTAL * 256);
#pragma unroll
        for (int rt = 0; rt < 2; rt++)
#pragma unroll
            for (int ct = 0; ct < 4; ct++) {
                f32x4 o = acc[rt][ct] + accsh[((h * 2 + rt) * 4 + ct) * 64 + lane];
#pragma unroll
                for (int rr = 0; rr < 4; rr++) {  // D: col=lane&15, row=quad*4+rr
                    int row = i0 + rt * 16 + quad * 4 + rr;
                    out[(size_t)row * 256 + h * 64 + ct * 16 + c16] = o[rr];
                }
            }
    }
}

// ---------------- h = 0.5*relu(sum of 4 partials) + 0.5*h (float4) --------------------
__global__ void k_epilogue(const float* hnp, float* h) {
    int idx = blockIdx.x * 256 + threadIdx.x;
    const float4* p0 = (const float4*)hnp;
    const float4* p1 = (const float4*)(hnp + (size_t)TOTAL * 256);
    const float4* p2 = (const float4*)(hnp + (size_t)2 * TOTAL * 256);
    const float4* p3 = (const float4*)(hnp + (size_t)3 * TOTAL * 256);
    float4* h4 = (float4*)h;
    float4 a = p0[idx], b = p1[idx], c = p2[idx], d = p3[idx], hh = h4[idx];
    hh.x = 0.5f * fmaxf(a.x + b.x + c.x + d.x, 0.f) + 0.5f * hh.x;
    hh.y = 0.5f * fmaxf(a.y + b.y + c.y + d.y, 0.f) + 0.5f * hh.y;
    hh.z = 0.5f * fmaxf(a.z + b.z + c.z + d.z, 0.f) + 0.5f * hh.z;
    hh.w = 0.5f * fmaxf(a.w + b.w + c.w + d.w, 0.f) + 0.5f * hh.w;
    h4[idx] = hh;
}

// ---------------- final scores + cos ---------------------------------------------------
__global__ void k_scores(const float* h, float* scoresv, float* cosv) {
    __shared__ float red[12];
    int n = blockIdx.x, t = threadIdx.x;
    int row = 1 + MD + n;
    float qv = h[t], sv = h[(size_t)row * 256 + t];
    float a = qv * qv, b = sv * sv, c = qv * sv;
    for (int o = 32; o > 0; o >>= 1) {
        a += __shfl_down(a, o); b += __shfl_down(b, o); c += __shfl_down(c, o);
    }
    int w = t >> 6;
    if ((t & 63) == 0) { red[w] = a; red[4 + w] = b; red[8 + w] = c; }
    __syncthreads();
    if (t == 0) {
        float qq = red[0] + red[1] + red[2] + red[3];
        float ss = red[4] + red[5] + red[6] + red[7];
        float qs = red[8] + red[9] + red[10] + red[11];
        scoresv[n] = qs * (1.f / 16.f);
        cosv[n] = qs / ((sqrtf(qq) + 1e-8f) * (sqrtf(ss) + 1e-8f));
    }
}

// ---------------- softmax over scores (single block) ----------------------------------
__global__ void k_softmax(const float* scoresv, float* awv) {
    __shared__ float red[4];
    int t = threadIdx.x;
    float m = -__builtin_inff();
    for (int n = t; n < NDOCS; n += 256) m = fmaxf(m, scoresv[n]);
    for (int o = 32; o > 0; o >>= 1) m = fmaxf(m, __shfl_down(m, o));
    if ((t & 63) == 0) red[t >> 6] = m;
    __syncthreads();
    m = fmaxf(fmaxf(red[0], red[1]), fmaxf(red[2], red[3]));
    __syncthreads();
    float s = 0.f;
    for (int n = t; n < NDOCS; n += 256) s += __expf(scoresv[n] - m);
    for (int o = 32; o > 0; o >>= 1) s += __shfl_down(s, o);
    if ((t & 63) == 0) red[t >> 6] = s;
    __syncthreads();
    s = red[0] + red[1] + red[2] + red[3];
    float inv = 1.f / s;
    for (int n = t; n < NDOCS; n += 256) awv[n] = __expf(scoresv[n] - m) * inv;
}

// ---------------- fused feature GEMM + output ----------------------------------------
#define TN 8
__global__ __launch_bounds__(256) void k_fusion(const float* h, const float* awv,
                                                const float* cosv, const float* fwT,
                                                const void* fusion_b, const void* out_w,
                                                const void* out_bp, void* outv,
                                                const int* flagp) {
    __shared__ float feats[TN][516];
    __shared__ float qhs[256];
    __shared__ float red[TN][4];
    int isbf = flagp[0];
    int t = threadIdx.x;
    int n0 = blockIdx.x * TN;
    qhs[t] = h[t];
    __syncthreads();
    for (int idx = t; idx < TN * 514; idx += 256) {
        int r = idx / 514, j = idx % 514;
        int n = n0 + r;
        float v = 0.f;
        if (n < NDOCS) {
            if (j < 256) v = h[(size_t)(1 + MD + n) * 256 + j];
            else if (j < 512) v = qhs[j - 256] * (awv[n] + 0.5f);
            else if (j == 512) v = cosv[n];
            else v = awv[n];
        }
        feats[r][j] = v;
    }
    __syncthreads();
    float acc[TN];
    float bk = ldf(fusion_b, t, isbf);
#pragma unroll
    for (int r = 0; r < TN; r++) acc[r] = bk;
    for (int j0 = 0; j0 < 512; j0 += 8) {        // 8 independent weight loads in flight
        float wv[8];
#pragma unroll
        for (int u = 0; u < 8; u++) wv[u] = fwT[(j0 + u) * 256 + t];
#pragma unroll
        for (int u = 0; u < 8; u++)
#pragma unroll
            for (int r = 0; r < TN; r++) acc[r] = fmaf(feats[r][j0 + u], wv[u], acc[r]);
    }
#pragma unroll
    for (int j = 512; j < 514; j++) {
        float wv = fwT[j * 256 + t];
#pragma unroll
        for (int r = 0; r < TN; r++) acc[r] = fmaf(feats[r][j], wv, acc[r]);
    }
    float ow = ldf(out_w, t, isbf);
    float outb = ldf(out_bp, 0, isbf);
#pragma unroll
    for (int r = 0; r < TN; r++) {
        float o = fmaxf(acc[r], 0.f) * ow;
        for (int off = 32; off > 0; off >>= 1) o += __shfl_down(o, off);
        if ((t & 63) == 0) red[r][t >> 6] = o;
    }
    __syncthreads();
    if (t < TN) {
        int n = n0 + t;
        if (n < NDOCS) {
            float o = red[t][0] + red[t][1] + red[t][2] + red[t][3] + outb + 0.5f * cosv[n];
            if (isbf) ((bf16*)outv)[n] = __float2bfloat16(o);
            else      ((float*)outv)[n] = o;
        }
    }
}

extern "C" void kernel_launch(void* const* d_in, const int* in_sizes, int n_in,
                              void* d_out, int out_size, void* d_ws, size_t ws_size,
                              hipStream_t stream) {
    const void* emb      = d_in[0];
    const int*  adj      = (const int*)d_in[1];
    const void* proj_w   = d_in[3];
    const void* proj_b   = d_in[4];
    const void* ln_scale = d_in[5];
    const void* ln_bias  = d_in[6];
    const void* gat_W    = d_in[7];
    const void* gat_a    = d_in[8];
    const void* fusion_w = d_in[9];
    const void* fusion_b = d_in[10];
    const void* out_w    = d_in[11];
    const void* out_b    = d_in[12];

    unsigned long long* maskb = (unsigned long long*)d_ws;
    int* flag = (int*)((char*)d_ws + (size_t)4096 * 64 * 8);
    float* f = (float*)((char*)d_ws + (size_t)4096 * 64 * 8 + 256);
    float* h       = f; f += 4096 * 256;
    float* srcb    = f; f += 4 * 4096;
    float* dstb    = f; f += 4 * 4096;
    float* mrow    = f; f += 4 * 4096;
    float* lrow    = f; f += 4 * 4096;
    float2* dpre   = (float2*)f; f += 2 * 4 * 4096;
    float* projT   = f; f += EMB * 256;
    float* gatT    = f; f += 2 * 256 * 256;
    float* fwT     = f; f += 514 * 256;
    float* scoresv = f; f += 4096;
    float* cosv    = f; f += 4096;
    float* awv     = f; f += 4096;
    ushort_t* whswz = (ushort_t*)f; f += 4096 * 256 / 2;   // 2MB
    float* hnp     = f; f += (size_t)JS * 4096 * 256;      // 16MB partials

    k_detect<<<dim3(1), dim3(256), 0, stream>>>((const uint16_t*)emb, flag);
    k_transpose<<<dim3(1410), dim3(256), 0, stream>>>(proj_w, gat_W, fusion_w, projT, gatT, fwT, flag);
    k_adjmask<<<dim3(4096), dim3(256), 0, stream>>>(adj, maskb);
    k_proj<<<dim3(TOTAL / PR), dim3(256), 0, stream>>>(emb, proj_b, projT, h, flag);
    k_cosupdate<<<dim3(128), dim3(256), 0, stream>>>(h);
    for (int layer = 0; layer < 2; layer++) {
        k_ln_wh<<<dim3(TOTAL / LR), dim3(256), 0, stream>>>(h, gatT, ln_scale, ln_bias, gat_a,
                                                            whswz, srcb, dstb, dpre, layer, flag);
        k_stats<<<dim3(4096), dim3(256), 0, stream>>>(srcb, dstb, maskb, mrow, lrow);
        k_pv<<<dim3(TOTAL / TI, JS), dim3(512), 0, stream>>>(whswz, srcb, mrow, lrow, dpre,
                                                             maskb, hnp);
        k_epilogue<<<dim3(1024), dim3(256), 0, stream>>>(hnp, h);
    }
    k_scores<<<dim3(NDOCS), dim3(256), 0, stream>>>(h, scoresv, cosv);
    k_softmax<<<dim3(1), dim3(256), 0, stream>>>(scoresv, awv);
    k_fusion<<<dim3((NDOCS + TN - 1) / TN), dim3(256), 0, stream>>>(h, awv, cosv, fwT,
                                                                    fusion_b, out_w, out_b,
                                                                    (void*)d_out, flag);
}

// Round 6
// 357.109 us; speedup vs baseline: 2.4668x; 1.2772x over previous
//
#include <hip/hip_runtime.h>
#include <hip/hip_bf16.h>
#include <stdint.h>

#define TOTAL 4096
#define EMB 384
#define MD 32
#define NDOCS (TOTAL - 1 - MD)   // 4063
#define LN_EPS 1e-5f

typedef __hip_bfloat16 bf16;
typedef unsigned short ushort_t;
typedef __attribute__((ext_vector_type(8))) short short8;
typedef __attribute__((ext_vector_type(4))) float f32x4;

// Dual-dtype load: inputs may be stored bf16 or fp32; isbf selects at runtime.
__device__ __forceinline__ float ldf(const void* p, int i, int isbf) {
    return isbf ? __bfloat162float(((const bf16*)p)[i]) : ((const float*)p)[i];
}

// round-half-up f32 -> bf16 bits (2 ops; bias <= 0.5 ulp, inputs finite)
__device__ __forceinline__ ushort_t f2bf(float x) {
    return (ushort_t)((__float_as_uint(x) + 0x8000u) >> 16);
}

// ---------------- detect storage dtype of float inputs --------------------------------
__global__ void k_detect(const uint16_t* p, int* flag) {
    __shared__ int red[4];
    int t = threadIdx.x;
    int cnt = 0;
    for (int k = t; k < 4096; k += 256) {
        uint16_t w = p[2 * k];
        int e = (w >> 7) & 0xFF;
        if (e >= 100 && e <= 140) cnt++;
    }
    for (int o = 32; o > 0; o >>= 1) cnt += __shfl_down(cnt, o);
    if ((t & 63) == 0) red[t >> 6] = cnt;
    __syncthreads();
    if (t == 0) flag[0] = (red[0] + red[1] + red[2] + red[3] > 2048) ? 1 : 0;
}

// ---------------- transpose weights (-> fp32, transposed for coalesced reads) ---------
__global__ void k_transpose(const void* proj_w, const void* gat_W, const void* fusion_w,
                            float* projT, float* gatT, float* fwT, const int* flagp) {
    int isbf = flagp[0];
    int idx = blockIdx.x * 256 + threadIdx.x;
    if (idx < EMB * 256) {                      // projT[d*256+c] = proj_w[c*EMB+d]
        int d = idx >> 8, c = idx & 255;
        projT[idx] = ldf(proj_w, c * EMB + d, isbf);
    } else if (idx < EMB * 256 + 2 * 256 * 256) {
        int r = idx - EMB * 256;
        int l = r >> 16; int rem = r & 65535;
        int d = rem >> 8, c = rem & 255;        // gatT[l][d*256+c] = gat_W[l][c*256+d]
        gatT[r] = ldf(gat_W, l * 65536 + c * 256 + d, isbf);
    } else if (idx < EMB * 256 + 2 * 256 * 256 + 514 * 256) {
        int r = idx - (EMB * 256 + 2 * 256 * 256);
        int j = r >> 8, c = r & 255;            // fwT[j*256+c] = fusion_w[c*514+j]
        fwT[r] = ldf(fusion_w, c * 514 + j, isbf);
    }
}

// ---------------- adj -> per-row bitmask (bit set = edge present) --------------------
__global__ void k_adjmask(const int* adj, unsigned long long* maskb) {
    int i = blockIdx.x;
    int t = threadIdx.x;
    int w = t >> 6, l = t & 63;
    for (int c = w; c < 64; c += 4) {
        int a = adj[(size_t)i * TOTAL + c * 64 + l];
        unsigned long long m = __ballot(a != 0);
        if (l == 0) maskb[i * 64 + c] = m;
    }
}

// ---------------- h = relu(emb @ projT + b), 8 rows/block -----------------------------
#define PR 8
__global__ void k_proj(const void* emb, const void* proj_b, const float* projT, float* h,
                       const int* flagp) {
    __shared__ float xs[PR][EMB];
    int isbf = flagp[0];
    int i0 = blockIdx.x * PR, t = threadIdx.x;
    for (int idx = t; idx < PR * EMB; idx += 256) {
        int r = idx / EMB, d = idx % EMB;
        xs[r][d] = ldf(emb, (i0 + r) * EMB + d, isbf);
    }
    __syncthreads();
    float acc[PR];
    float bias = ldf(proj_b, t, isbf);
#pragma unroll
    for (int r = 0; r < PR; r++) acc[r] = bias;
    for (int d = 0; d < EMB; d++) {
        float wv = projT[d * 256 + t];
#pragma unroll
        for (int r = 0; r < PR; r++) acc[r] = fmaf(xs[r][d], wv, acc[r]);
    }
#pragma unroll
    for (int r = 0; r < PR; r++) h[(size_t)(i0 + r) * 256 + t] = fmaxf(acc[r], 0.f);
}

// ---------------- query-aware doc update: s += 0.8*cos(q,s)*q (wave-per-row) ----------
__global__ __launch_bounds__(256) void k_cosupdate(float* h) {
    int t = threadIdx.x, W = t >> 6, lane = t & 63;
    float4* h4 = (float4*)h;
    float4 q4 = h4[lane];
    float a = q4.x * q4.x + q4.y * q4.y + q4.z * q4.z + q4.w * q4.w;
    for (int o = 32; o > 0; o >>= 1) a += __shfl_xor(a, o);
    float qn = sqrtf(a) + 1e-8f;
    int gw = blockIdx.x * 4 + W;
    for (int n = gw; n < NDOCS; n += 1024) {
        size_t ro = (size_t)(1 + MD + n) * 64;
        float4 s4 = h4[ro + lane];
        float b = s4.x * s4.x + s4.y * s4.y + s4.z * s4.z + s4.w * s4.w;
        float c = q4.x * s4.x + q4.y * s4.y + q4.z * s4.z + q4.w * s4.w;
        for (int o = 32; o > 0; o >>= 1) { b += __shfl_xor(b, o); c += __shfl_xor(c, o); }
        float k = 0.8f * (c / (qn * (sqrtf(b) + 1e-8f)));
        s4.x += k * q4.x; s4.y += k * q4.y; s4.z += k * q4.z; s4.w += k * q4.w;
        h4[ro + lane] = s4;
    }
}

// ---------------- layernorm + Wh GEMM + src/dst; Wh emitted bf16 B-frag-swizzled ------
// whswz (ushort): off = (j>>6)*16384 + (c>>6)*4096 + ((j>>3)&7)*512 + ((c>>4)&3)*128
//                       + (c&15)*8 + (j&7)
// -> each k_pv lane's 16B B-fragment is CONTIGUOUS IN GLOBAL MEMORY (no LDS staging).
// dpre[h][j] = (dst*log2e, 0.2*dst*log2e) pairs for fused exp2 p-compute.
#define LR 4
__global__ void k_ln_wh(const float* h, const float* gatT, const void* ln_scale,
                        const void* ln_bias, const void* gat_a,
                        ushort_t* whswz, float* srcb, float* dstb, float2* dpre,
                        int layer, const int* flagp) {
    __shared__ float xs[LR][256];
    __shared__ float red[2][LR][4];
    int isbf = flagp[0];
    int i0 = blockIdx.x * LR, t = threadIdx.x;
    int w = t >> 6, l = t & 63;
    float scale = ldf(ln_scale, layer * 256 + t, isbf);
    float bias = ldf(ln_bias, layer * 256 + t, isbf);
    float hv[LR];
#pragma unroll
    for (int r = 0; r < LR; r++) hv[r] = h[(size_t)(i0 + r) * 256 + t];
#pragma unroll
    for (int r = 0; r < LR; r++) {
        float a = hv[r], b = hv[r] * hv[r];
        for (int o = 32; o > 0; o >>= 1) { a += __shfl_down(a, o); b += __shfl_down(b, o); }
        if (l == 0) { red[0][r][w] = a; red[1][r][w] = b; }
    }
    __syncthreads();
#pragma unroll
    for (int r = 0; r < LR; r++) {
        float mu = (red[0][r][0] + red[0][r][1] + red[0][r][2] + red[0][r][3]) * (1.f / 256.f);
        float var = (red[1][r][0] + red[1][r][1] + red[1][r][2] + red[1][r][3]) * (1.f / 256.f) - mu * mu;
        float x = (hv[r] - mu) * rsqrtf(var + LN_EPS) * scale + bias;
        xs[r][t] = x;
    }
    __syncthreads();
    const float* gT = gatT + layer * 65536;
    float acc[LR] = {0.f, 0.f, 0.f, 0.f};
    for (int d = 0; d < 256; d++) {
        float wv = gT[d * 256 + t];
#pragma unroll
        for (int r = 0; r < LR; r++) acc[r] = fmaf(xs[r][d], wv, acc[r]);
    }
    float av1 = ldf(gat_a, layer * 512 + w * 128 + l, isbf);
    float av2 = ldf(gat_a, layer * 512 + w * 128 + 64 + l, isbf);
    const float LOG2E = 1.44269504f;
#pragma unroll
    for (int r = 0; r < LR; r++) {
        int i = i0 + r;
        int off = (i >> 6) * 16384 + (t >> 6) * 4096 + ((i >> 3) & 7) * 512 +
                  ((t >> 4) & 3) * 128 + (t & 15) * 8 + (i & 7);
        whswz[off] = f2bf(acc[r]);
        float sv = acc[r] * av1, dv = acc[r] * av2;
        for (int o = 32; o > 0; o >>= 1) { sv += __shfl_down(sv, o); dv += __shfl_down(dv, o); }
        if (l == 0) {
            srcb[w * 4096 + i] = sv;
            dstb[w * 4096 + i] = dv;
            dpre[w * 4096 + i] = make_float2(dv * LOG2E, 0.2f * dv * LOG2E);
        }
    }
}

// ---------------- per-head global max of dst (softmax shift upper bound) --------------
__global__ void k_dmax(const float* dstb, float* dmax) {
    __shared__ float red[4];
    int h = blockIdx.x, t = threadIdx.x;
    float m = -__builtin_inff();
    for (int j = t; j < 4096; j += 256) m = fmaxf(m, dstb[h * 4096 + j]);
    for (int o = 32; o > 0; o >>= 1) m = fmaxf(m, __shfl_down(m, o));
    if ((t & 63) == 0) red[t >> 6] = m;
    __syncthreads();
    if (t == 0) dmax[h] = fmaxf(fmaxf(red[0], red[1]), fmaxf(red[2], red[3]));
}

// ---------------- PV via MFMA, barrier-free K-loop, unnormalized-exp ------------------
// Grid: (128 i-tiles of 32 rows) x (4 j-splits of 1024). Block: 512 thr = 8 waves
// = 4 heads x 2 k-quarters. Each wave register-prefetches its own contiguous B-frags.
// pu = exp2(max(s1+d1[j], s2+d2[j])) with shift mhat = lrelu(src+dmax) >= true max.
// Row-sums of pu accumulate in-register -> lpart; epilogue divides (softmax shift-inv).
#define TI 32
#define JS 4
__global__ __launch_bounds__(512) void k_pv(const ushort_t* whswz, const float* srcb,
                                            const float* dmax, const float2* dpre,
                                            const unsigned long long* maskb,
                                            float* hnp, float* lpart) {
    __shared__ unsigned long long mbs[TI][17];
    __shared__ float2 dpres[4][1024];            // 32KB; aliased by accsh after the loop
    __shared__ float srcs[4][TI], rces[4][TI];
    f32x4* accsh = (f32x4*)dpres;
    int t = threadIdx.x;
    int W = t >> 6, lane = t & 63;
    int h = W & 3, kq = W >> 2;
    int quad = lane >> 4, c16 = lane & 15;
    int i0 = blockIdx.x * TI;
    int jbase = blockIdx.y * 1024;
    for (int idx = t; idx < TI * 16; idx += 512) {
        int r = idx >> 4, wd = idx & 15;
        mbs[r][wd] = maskb[(size_t)(i0 + r) * 64 + (jbase >> 6) + wd];
    }
    for (int idx = t; idx < 4096; idx += 512) {
        int hh = idx >> 10, jl = idx & 1023;
        dpres[hh][jl] = dpre[hh * 4096 + jbase + jl];
    }
    if (t < 128) {
        int h2 = t >> 5, r = t & 31;
        float sv = srcb[h2 * 4096 + i0 + r];
        srcs[h2][r] = sv;
        float sd = sv + dmax[h2];
        rces[h2][r] = -fmaxf(sd, 0.2f * sd);     // -mhat
    }
    __syncthreads();
    const float LOG2E = 1.44269504f;
    float s1[2], s2[2], psum[2] = {0.f, 0.f};
#pragma unroll
    for (int rt = 0; rt < 2; rt++) {
        float src = srcs[h][rt * 16 + c16], rce = rces[h][rt * 16 + c16];
        s1[rt] = (src + rce) * LOG2E;
        s2[rt] = (0.2f * src + rce) * LOG2E;
    }
    f32x4 acc[2][4];
#pragma unroll
    for (int rt = 0; rt < 2; rt++)
#pragma unroll
        for (int ct = 0; ct < 4; ct++) acc[rt][ct] = (f32x4){0.f, 0.f, 0.f, 0.f};
    const uint4* g4 = (const uint4*)whswz;
    size_t b0 = (size_t)(jbase >> 6) * 2048 + h * 512 + (kq * 4 + quad) * 64 + c16;
    uint4 bn[4];
#pragma unroll
    for (int ct = 0; ct < 4; ct++) bn[ct] = g4[b0 + ct * 16];
    for (int step = 0; step < 16; step++) {
        uint4 bc[4];
#pragma unroll
        for (int ct = 0; ct < 4; ct++) bc[ct] = bn[ct];
        if (step < 15) {
            size_t bs = b0 + (size_t)(step + 1) * 2048;
#pragma unroll
            for (int ct = 0; ct < 4; ct++) bn[ct] = g4[bs + ct * 16];
        }
        int jl0 = step * 64 + kq * 32 + quad * 8;
        unsigned int mby[2];
#pragma unroll
        for (int rt = 0; rt < 2; rt++)
            mby[rt] = (unsigned int)(mbs[rt * 16 + c16][step] >> (kq * 32 + quad * 8)) & 0xFFu;
        const float4* dp4 = (const float4*)&dpres[h][jl0];
        float4 dv[4];
#pragma unroll
        for (int q = 0; q < 4; q++) dv[q] = dp4[q];
        short8 af[2];
#pragma unroll
        for (int rt = 0; rt < 2; rt++) {
#pragma unroll
            for (int q = 0; q < 4; q++) {
                float4 d = dv[q];
                float pa = exp2f(fmaxf(s1[rt] + d.x, s2[rt] + d.y));
                float pb = exp2f(fmaxf(s1[rt] + d.z, s2[rt] + d.w));
                pa = ((mby[rt] >> (2 * q)) & 1u) ? pa : 0.f;
                pb = ((mby[rt] >> (2 * q + 1)) & 1u) ? pb : 0.f;
                psum[rt] += pa + pb;
                af[rt][2 * q] = (short)f2bf(pa);
                af[rt][2 * q + 1] = (short)f2bf(pb);
            }
        }
#pragma unroll
        for (int ct = 0; ct < 4; ct++) {
            short8 bf = __builtin_bit_cast(short8, bc[ct]);
            acc[0][ct] = __builtin_amdgcn_mfma_f32_16x16x32_bf16(af[0], bf, acc[0][ct], 0, 0, 0);
            acc[1][ct] = __builtin_amdgcn_mfma_f32_16x16x32_bf16(af[1], bf, acc[1][ct], 0, 0, 0);
        }
    }
#pragma unroll
    for (int rt = 0; rt < 2; rt++) {             // row-sum: reduce over quad (lane bits 4-5)
        float ps = psum[rt];
        ps += __shfl_xor(ps, 16);
        ps += __shfl_xor(ps, 32);
        if (quad == 0)
            lpart[((blockIdx.y * 4 + h) * 2 + kq) * 4096 + i0 + rt * 16 + c16] = ps;
    }
    __syncthreads();                              // dpres dead; reuse as accsh
    if (kq == 1) {
#pragma unroll
        for (int rt = 0; rt < 2; rt++)
#pragma unroll
            for (int ct = 0; ct < 4; ct++)
                accsh[((h * 2 + rt) * 4 + ct) * 64 + lane] = acc[rt][ct];
    }
    __syncthreads();
    if (kq == 0) {
        float* out = hnp + (size_t)blockIdx.y * (TOTAL * 256);
#pragma unroll
        for (int rt = 0; rt < 2; rt++)
#pragma unroll
            for (int ct = 0; ct < 4; ct++) {
                f32x4 o = acc[rt][ct] + accsh[((h * 2 + rt) * 4 + ct) * 64 + lane];
#pragma unroll
                for (int rr = 0; rr < 4; rr++) {  // D: col=lane&15, row=quad*4+rr
                    int row = i0 + rt * 16 + quad * 4 + rr;
                    out[(size_t)row * 256 + h * 64 + ct * 16 + c16] = o[rr];
                }
            }
    }
}

// ---------------- h = 0.5*relu((sum partials)/l) + 0.5*h (float4) ---------------------
__global__ void k_epilogue(const float* hnp, const float* lpart, float* h) {
    int idx = blockIdx.x * 256 + threadIdx.x;     // float4 index
    int row = idx >> 6, hh_ = (idx >> 4) & 3;
    float l = 0.f;
#pragma unroll
    for (int js = 0; js < 4; js++)
#pragma unroll
        for (int kq = 0; kq < 2; kq++)
            l += lpart[((js * 4 + hh_) * 2 + kq) * 4096 + row];
    float inv = 1.f / l;
    const float4* p0 = (const float4*)hnp;
    const float4* p1 = (const float4*)(hnp + (size_t)TOTAL * 256);
    const float4* p2 = (const float4*)(hnp + (size_t)2 * TOTAL * 256);
    const float4* p3 = (const float4*)(hnp + (size_t)3 * TOTAL * 256);
    float4* h4 = (float4*)h;
    float4 a = p0[idx], b = p1[idx], c = p2[idx], d = p3[idx], hh = h4[idx];
    hh.x = 0.5f * fmaxf((a.x + b.x + c.x + d.x) * inv, 0.f) + 0.5f * hh.x;
    hh.y = 0.5f * fmaxf((a.y + b.y + c.y + d.y) * inv, 0.f) + 0.5f * hh.y;
    hh.z = 0.5f * fmaxf((a.z + b.z + c.z + d.z) * inv, 0.f) + 0.5f * hh.z;
    hh.w = 0.5f * fmaxf((a.w + b.w + c.w + d.w) * inv, 0.f) + 0.5f * hh.w;
    h4[idx] = hh;
}

// ---------------- final scores + cos (wave-per-row) -----------------------------------
__global__ __launch_bounds__(256) void k_scores(const float* h, float* scoresv, float* cosv) {
    int t = threadIdx.x, W = t >> 6, lane = t & 63;
    const float4* h4 = (const float4*)h;
    float4 q4 = h4[lane];
    float a = q4.x * q4.x + q4.y * q4.y + q4.z * q4.z + q4.w * q4.w;
    for (int o = 32; o > 0; o >>= 1) a += __shfl_xor(a, o);
    float qn = sqrtf(a) + 1e-8f;
    int gw = blockIdx.x * 4 + W;
    for (int n = gw; n < NDOCS; n += 1024) {
        size_t ro = (size_t)(1 + MD + n) * 64;
        float4 s4 = h4[ro + lane];
        float b = s4.x * s4.x + s4.y * s4.y + s4.z * s4.z + s4.w * s4.w;
        float c = q4.x * s4.x + q4.y * s4.y + q4.z * s4.z + q4.w * s4.w;
        for (int o = 32; o > 0; o >>= 1) { b += __shfl_xor(b, o); c += __shfl_xor(c, o); }
        if (lane == 0) {
            scoresv[n] = c * (1.f / 16.f);
            cosv[n] = c / (qn * (sqrtf(b) + 1e-8f));
        }
    }
}

// ---------------- softmax over scores (single block) ----------------------------------
__global__ void k_softmax(const float* scoresv, float* awv) {
    __shared__ float red[4];
    int t = threadIdx.x;
    float m = -__builtin_inff();
    for (int n = t; n < NDOCS; n += 256) m = fmaxf(m, scoresv[n]);
    for (int o = 32; o > 0; o >>= 1) m = fmaxf(m, __shfl_down(m, o));
    if ((t & 63) == 0) red[t >> 6] = m;
    __syncthreads();
    m = fmaxf(fmaxf(red[0], red[1]), fmaxf(red[2], red[3]));
    __syncthreads();
    float s = 0.f;
    for (int n = t; n < NDOCS; n += 256) s += __expf(scoresv[n] - m);
    for (int o = 32; o > 0; o >>= 1) s += __shfl_down(s, o);
    if ((t & 63) == 0) red[t >> 6] = s;
    __syncthreads();
    s = red[0] + red[1] + red[2] + red[3];
    float inv = 1.f / s;
    for (int n = t; n < NDOCS; n += 256) awv[n] = __expf(scoresv[n] - m) * inv;
}

// ---------------- fused feature GEMM + output ----------------------------------------
#define TN 8
__global__ __launch_bounds__(256) void k_fusion(const float* h, const float* awv,
                                                const float* cosv, const float* fwT,
                                                const void* fusion_b, const void* out_w,
                                                const void* out_bp, void* outv,
                                                const int* flagp) {
    __shared__ float feats[TN][516];
    __shared__ float qhs[256];
    __shared__ float red[TN][4];
    int isbf = flagp[0];
    int t = threadIdx.x;
    int n0 = blockIdx.x * TN;
    qhs[t] = h[t];
    __syncthreads();
    for (int idx = t; idx < TN * 514; idx += 256) {
        int r = idx / 514, j = idx % 514;
        int n = n0 + r;
        float v = 0.f;
        if (n < NDOCS) {
            if (j < 256) v = h[(size_t)(1 + MD + n) * 256 + j];
            else if (j < 512) v = qhs[j - 256] * (awv[n] + 0.5f);
            else if (j == 512) v = cosv[n];
            else v = awv[n];
        }
        feats[r][j] = v;
    }
    __syncthreads();
    float acc[TN];
    float bk = ldf(fusion_b, t, isbf);
#pragma unroll
    for (int r = 0; r < TN; r++) acc[r] = bk;
    for (int j0 = 0; j0 < 512; j0 += 8) {        // 8 independent weight loads in flight
        float wv[8];
#pragma unroll
        for (int u = 0; u < 8; u++) wv[u] = fwT[(j0 + u) * 256 + t];
#pragma unroll
        for (int u = 0; u < 8; u++)
#pragma unroll
            for (int r = 0; r < TN; r++) acc[r] = fmaf(feats[r][j0 + u], wv[u], acc[r]);
    }
#pragma unroll
    for (int j = 512; j < 514; j++) {
        float wv = fwT[j * 256 + t];
#pragma unroll
        for (int r = 0; r < TN; r++) acc[r] = fmaf(feats[r][j], wv, acc[r]);
    }
    float ow = ldf(out_w, t, isbf);
    float outb = ldf(out_bp, 0, isbf);
#pragma unroll
    for (int r = 0; r < TN; r++) {
        float o = fmaxf(acc[r], 0.f) * ow;
        for (int off = 32; off > 0; off >>= 1) o += __shfl_down(o, off);
        if ((t & 63) == 0) red[r][t >> 6] = o;
    }
    __syncthreads();
    if (t < TN) {
        int n = n0 + t;
        if (n < NDOCS) {
            float o = red[t][0] + red[t][1] + red[t][2] + red[t][3] + outb + 0.5f * cosv[n];
            if (isbf) ((bf16*)outv)[n] = __float2bfloat16(o);
            else      ((float*)outv)[n] = o;
        }
    }
}

extern "C" void kernel_launch(void* const* d_in, const int* in_sizes, int n_in,
                              void* d_out, int out_size, void* d_ws, size_t ws_size,
                              hipStream_t stream) {
    const void* emb      = d_in[0];
    const int*  adj      = (const int*)d_in[1];
    const void* proj_w   = d_in[3];
    const void* proj_b   = d_in[4];
    const void* ln_scale = d_in[5];
    const void* ln_bias  = d_in[6];
    const void* gat_W    = d_in[7];
    const void* gat_a    = d_in[8];
    const void* fusion_w = d_in[9];
    const void* fusion_b = d_in[10];
    const void* out_w    = d_in[11];
    const void* out_b    = d_in[12];

    unsigned long long* maskb = (unsigned long long*)d_ws;
    int* flag = (int*)((char*)d_ws + (size_t)4096 * 64 * 8);
    float* f = (float*)((char*)d_ws + (size_t)4096 * 64 * 8 + 256);
    float* h       = f; f += 4096 * 256;
    float* srcb    = f; f += 4 * 4096;
    float* dstb    = f; f += 4 * 4096;
    float2* dpre   = (float2*)f; f += 2 * 4 * 4096;
    float* dmax    = f; f += 64;
    float* projT   = f; f += EMB * 256;
    float* gatT    = f; f += 2 * 256 * 256;
    float* fwT     = f; f += 514 * 256;
    float* scoresv = f; f += 4096;
    float* cosv    = f; f += 4096;
    float* awv     = f; f += 4096;
    float* lpart   = f; f += 4 * 4 * 2 * 4096;             // 512KB
    ushort_t* whswz = (ushort_t*)f; f += 4096 * 256 / 2;   // 2MB
    float* hnp     = f; f += (size_t)JS * 4096 * 256;      // 16MB partials

    k_detect<<<dim3(1), dim3(256), 0, stream>>>((const uint16_t*)emb, flag);
    k_transpose<<<dim3(1410), dim3(256), 0, stream>>>(proj_w, gat_W, fusion_w, projT, gatT, fwT, flag);
    k_adjmask<<<dim3(4096), dim3(256), 0, stream>>>(adj, maskb);
    k_proj<<<dim3(TOTAL / PR), dim3(256), 0, stream>>>(emb, proj_b, projT, h, flag);
    k_cosupdate<<<dim3(256), dim3(256), 0, stream>>>(h);
    for (int layer = 0; layer < 2; layer++) {
        k_ln_wh<<<dim3(TOTAL / LR), dim3(256), 0, stream>>>(h, gatT, ln_scale, ln_bias, gat_a,
                                                            whswz, srcb, dstb, dpre, layer, flag);
        k_dmax<<<dim3(4), dim3(256), 0, stream>>>(dstb, dmax);
        k_pv<<<dim3(TOTAL / TI, JS), dim3(512), 0, stream>>>(whswz, srcb, dmax, dpre,
                                                             maskb, hnp, lpart);
        k_epilogue<<<dim3(1024), dim3(256), 0, stream>>>(hnp, lpart, h);
    }
    k_scores<<<dim3(256), dim3(256), 0, stream>>>(h, scoresv, cosv);
    k_softmax<<<dim3(1), dim3(256), 0, stream>>>(scoresv, awv);
    k_fusion<<<dim3((NDOCS + TN - 1) / TN), dim3(256), 0, stream>>>(h, awv, cosv, fwT,
                                                                    fusion_b, out_w, out_b,
                                                                    (void*)d_out, flag);
}

// Round 7
// 342.570 us; speedup vs baseline: 2.5715x; 1.0424x over previous
//
#include <hip/hip_runtime.h>
#include <hip/hip_bf16.h>
#include <stdint.h>

#define TOTAL 4096
#define EMB 384
#define MD 32
#define NDOCS (TOTAL - 1 - MD)   // 4063
#define LN_EPS 1e-5f

typedef __hip_bfloat16 bf16;
typedef unsigned short ushort_t;
typedef __attribute__((ext_vector_type(8))) short short8;
typedef __attribute__((ext_vector_type(4))) float f32x4;
typedef __attribute__((ext_vector_type(2))) float f32x2;

// Dual-dtype load: inputs may be stored bf16 or fp32; isbf selects at runtime.
__device__ __forceinline__ float ldf(const void* p, int i, int isbf) {
    return isbf ? __bfloat162float(((const bf16*)p)[i]) : ((const float*)p)[i];
}

// round-half-up f32 -> bf16 bits (2 ops; bias <= 0.5 ulp, inputs finite)
__device__ __forceinline__ ushort_t f2bf(float x) {
    return (ushort_t)((__float_as_uint(x) + 0x8000u) >> 16);
}

// ---------------- detect storage dtype of float inputs --------------------------------
__global__ void k_detect(const uint16_t* p, int* flag) {
    __shared__ int red[4];
    int t = threadIdx.x;
    int cnt = 0;
    for (int k = t; k < 4096; k += 256) {
        uint16_t w = p[2 * k];
        int e = (w >> 7) & 0xFF;
        if (e >= 100 && e <= 140) cnt++;
    }
    for (int o = 32; o > 0; o >>= 1) cnt += __shfl_down(cnt, o);
    if ((t & 63) == 0) red[t >> 6] = cnt;
    __syncthreads();
    if (t == 0) flag[0] = (red[0] + red[1] + red[2] + red[3] > 2048) ? 1 : 0;
}

// ---------------- transpose weights (-> fp32, transposed for coalesced reads) ---------
__global__ void k_transpose(const void* proj_w, const void* gat_W, const void* fusion_w,
                            float* projT, float* gatT, float* fwT, const int* flagp) {
    int isbf = flagp[0];
    int idx = blockIdx.x * 256 + threadIdx.x;
    if (idx < EMB * 256) {                      // projT[d*256+c] = proj_w[c*EMB+d]
        int d = idx >> 8, c = idx & 255;
        projT[idx] = ldf(proj_w, c * EMB + d, isbf);
    } else if (idx < EMB * 256 + 2 * 256 * 256) {
        int r = idx - EMB * 256;
        int l = r >> 16; int rem = r & 65535;
        int d = rem >> 8, c = rem & 255;        // gatT[l][d*256+c] = gat_W[l][c*256+d]
        gatT[r] = ldf(gat_W, l * 65536 + c * 256 + d, isbf);
    } else if (idx < EMB * 256 + 2 * 256 * 256 + 514 * 256) {
        int r = idx - (EMB * 256 + 2 * 256 * 256);
        int j = r >> 8, c = r & 255;            // fwT[j*256+c] = fusion_w[c*514+j]
        fwT[r] = ldf(fusion_w, c * 514 + j, isbf);
    }
}

// ---------------- adj -> per-row bitmask (bit set = edge present) --------------------
__global__ void k_adjmask(const int* adj, unsigned long long* maskb) {
    int i = blockIdx.x;
    int t = threadIdx.x;
    int w = t >> 6, l = t & 63;
    for (int c = w; c < 64; c += 4) {
        int a = adj[(size_t)i * TOTAL + c * 64 + l];
        unsigned long long m = __ballot(a != 0);
        if (l == 0) maskb[i * 64 + c] = m;
    }
}

// ---------------- h = relu(emb @ projT + b), 8 rows/block -----------------------------
#define PR 8
__global__ void k_proj(const void* emb, const void* proj_b, const float* projT, float* h,
                       const int* flagp) {
    __shared__ float xs[PR][EMB];
    int isbf = flagp[0];
    int i0 = blockIdx.x * PR, t = threadIdx.x;
    for (int idx = t; idx < PR * EMB; idx += 256) {
        int r = idx / EMB, d = idx % EMB;
        xs[r][d] = ldf(emb, (i0 + r) * EMB + d, isbf);
    }
    __syncthreads();
    float acc[PR];
    float bias = ldf(proj_b, t, isbf);
#pragma unroll
    for (int r = 0; r < PR; r++) acc[r] = bias;
    for (int d0 = 0; d0 < EMB; d0 += 4) {
        float w0 = projT[d0 * 256 + t];
        float w1 = projT[(d0 + 1) * 256 + t];
        float w2 = projT[(d0 + 2) * 256 + t];
        float w3 = projT[(d0 + 3) * 256 + t];
#pragma unroll
        for (int r = 0; r < PR; r++) {
            float4 x = *(const float4*)&xs[r][d0];
            acc[r] = fmaf(x.x, w0, acc[r]);
            acc[r] = fmaf(x.y, w1, acc[r]);
            acc[r] = fmaf(x.z, w2, acc[r]);
            acc[r] = fmaf(x.w, w3, acc[r]);
        }
    }
#pragma unroll
    for (int r = 0; r < PR; r++) h[(size_t)(i0 + r) * 256 + t] = fmaxf(acc[r], 0.f);
}

// ---------------- query-aware doc update: s += 0.8*cos(q,s)*q (wave-per-row) ----------
__global__ __launch_bounds__(256) void k_cosupdate(float* h) {
    int t = threadIdx.x, W = t >> 6, lane = t & 63;
    float4* h4 = (float4*)h;
    float4 q4 = h4[lane];
    float a = q4.x * q4.x + q4.y * q4.y + q4.z * q4.z + q4.w * q4.w;
    for (int o = 32; o > 0; o >>= 1) a += __shfl_xor(a, o);
    float qn = sqrtf(a) + 1e-8f;
    int gw = blockIdx.x * 4 + W;
    for (int n = gw; n < NDOCS; n += 1024) {
        size_t ro = (size_t)(1 + MD + n) * 64;
        float4 s4 = h4[ro + lane];
        float b = s4.x * s4.x + s4.y * s4.y + s4.z * s4.z + s4.w * s4.w;
        float c = q4.x * s4.x + q4.y * s4.y + q4.z * s4.z + q4.w * s4.w;
        for (int o = 32; o > 0; o >>= 1) { b += __shfl_xor(b, o); c += __shfl_xor(c, o); }
        float k = 0.8f * (c / (qn * (sqrtf(b) + 1e-8f)));
        s4.x += k * q4.x; s4.y += k * q4.y; s4.z += k * q4.z; s4.w += k * q4.w;
        h4[ro + lane] = s4;
    }
}

// ---------------- layernorm + Wh GEMM + src/dst; Wh emitted bf16 B-frag-swizzled ------
// whswz (ushort): off = (j>>6)*16384 + (c>>6)*4096 + ((j>>3)&7)*512 + ((c>>4)&3)*128
//                       + (c&15)*8 + (j&7)
// d1g/d2g (SoA): d1 = dst*log2e, d2 = 0.2*dst*log2e — packed-math friendly in k_pv.
#define LR 4
__global__ void k_ln_wh(const float* h, const float* gatT, const void* ln_scale,
                        const void* ln_bias, const void* gat_a,
                        ushort_t* whswz, float* srcb, float* dstb, float* d1g, float* d2g,
                        int layer, const int* flagp) {
    __shared__ float xs[LR][256];
    __shared__ float red[2][LR][4];
    int isbf = flagp[0];
    int i0 = blockIdx.x * LR, t = threadIdx.x;
    int w = t >> 6, l = t & 63;
    float scale = ldf(ln_scale, layer * 256 + t, isbf);
    float bias = ldf(ln_bias, layer * 256 + t, isbf);
    float hv[LR];
#pragma unroll
    for (int r = 0; r < LR; r++) hv[r] = h[(size_t)(i0 + r) * 256 + t];
#pragma unroll
    for (int r = 0; r < LR; r++) {
        float a = hv[r], b = hv[r] * hv[r];
        for (int o = 32; o > 0; o >>= 1) { a += __shfl_down(a, o); b += __shfl_down(b, o); }
        if (l == 0) { red[0][r][w] = a; red[1][r][w] = b; }
    }
    __syncthreads();
#pragma unroll
    for (int r = 0; r < LR; r++) {
        float mu = (red[0][r][0] + red[0][r][1] + red[0][r][2] + red[0][r][3]) * (1.f / 256.f);
        float var = (red[1][r][0] + red[1][r][1] + red[1][r][2] + red[1][r][3]) * (1.f / 256.f) - mu * mu;
        float x = (hv[r] - mu) * rsqrtf(var + LN_EPS) * scale + bias;
        xs[r][t] = x;
    }
    __syncthreads();
    const float* gT = gatT + layer * 65536;
    float acc[LR] = {0.f, 0.f, 0.f, 0.f};
    for (int d0 = 0; d0 < 256; d0 += 4) {
        float w0 = gT[d0 * 256 + t];
        float w1 = gT[(d0 + 1) * 256 + t];
        float w2 = gT[(d0 + 2) * 256 + t];
        float w3 = gT[(d0 + 3) * 256 + t];
#pragma unroll
        for (int r = 0; r < LR; r++) {
            float4 x = *(const float4*)&xs[r][d0];
            acc[r] = fmaf(x.x, w0, acc[r]);
            acc[r] = fmaf(x.y, w1, acc[r]);
            acc[r] = fmaf(x.z, w2, acc[r]);
            acc[r] = fmaf(x.w, w3, acc[r]);
        }
    }
    float av1 = ldf(gat_a, layer * 512 + w * 128 + l, isbf);
    float av2 = ldf(gat_a, layer * 512 + w * 128 + 64 + l, isbf);
    const float LOG2E = 1.44269504f;
#pragma unroll
    for (int r = 0; r < LR; r++) {
        int i = i0 + r;
        int off = (i >> 6) * 16384 + (t >> 6) * 4096 + ((i >> 3) & 7) * 512 +
                  ((t >> 4) & 3) * 128 + (t & 15) * 8 + (i & 7);
        whswz[off] = f2bf(acc[r]);
        float sv = acc[r] * av1, dv = acc[r] * av2;
        for (int o = 32; o > 0; o >>= 1) { sv += __shfl_down(sv, o); dv += __shfl_down(dv, o); }
        if (l == 0) {
            srcb[w * 4096 + i] = sv;
            dstb[w * 4096 + i] = dv;
            d1g[w * 4096 + i] = dv * LOG2E;
            d2g[w * 4096 + i] = 0.2f * dv * LOG2E;
        }
    }
}

// ---------------- per-head global max of dst (softmax shift upper bound) --------------
__global__ void k_dmax(const float* dstb, float* dmax) {
    __shared__ float red[4];
    int h = blockIdx.x, t = threadIdx.x;
    float m = -__builtin_inff();
    for (int j = t; j < 4096; j += 256) m = fmaxf(m, dstb[h * 4096 + j]);
    for (int o = 32; o > 0; o >>= 1) m = fmaxf(m, __shfl_down(m, o));
    if ((t & 63) == 0) red[t >> 6] = m;
    __syncthreads();
    if (t == 0) dmax[h] = fmaxf(fmaxf(red[0], red[1]), fmaxf(red[2], red[3]));
}

// ---------------- PV via MFMA, barrier-free K-loop, packed p-compute ------------------
// Grid: (128 i-tiles of 32 rows) x (4 j-splits of 1024). Block: 512 thr = 8 waves
// = 4 heads x 2 k-quarters. B-frags register-prefetched from contiguous global.
// p = exp2(pk_max(s1+d1[j], s2+d2[j])); mask applied as one v_and on the packed bf16
// pair via 4-entry LDS lut. Row-sum l computed by a 5th MFMA vs ones-column B-frag.
#define TI 32
#define JS 4
__global__ __launch_bounds__(512) void k_pv(const ushort_t* whswz, const float* srcb,
                                            const float* dmax, const float* d1g,
                                            const float* d2g,
                                            const unsigned long long* maskb,
                                            float* hnp, float* lpart) {
    __shared__ unsigned long long mbs[TI][17];
    __shared__ float d1s[4][1024];               // 16KB; aliased by accsh after the loop
    __shared__ float d2s[4][1024];               // 16KB
    __shared__ float srcs[4][TI], rces[4][TI];
    __shared__ unsigned int mlut[4];
    __shared__ __align__(16) float lsh[4][2][4][4];  // [h][rt][quad][rr] ones-col patch
    f32x4* accsh = (f32x4*)d1s;
    int t = threadIdx.x;
    int W = t >> 6, lane = t & 63;
    int h = W & 3, kq = W >> 2;
    int quad = lane >> 4, c16 = lane & 15;
    int i0 = blockIdx.x * TI;
    int jbase = blockIdx.y * 1024;
    if (t < 4) mlut[t] = (t & 1 ? 0x0000FFFFu : 0u) | (t & 2 ? 0xFFFF0000u : 0u);
    for (int idx = t; idx < TI * 16; idx += 512) {
        int r = idx >> 4, wd = idx & 15;
        mbs[r][wd] = maskb[(size_t)(i0 + r) * 64 + (jbase >> 6) + wd];
    }
    for (int idx = t; idx < 1024; idx += 512) {  // stage d1/d2 as float4
        int hh = idx >> 8, j4 = idx & 255;
        ((float4*)d1s)[idx] = ((const float4*)(d1g + hh * 4096 + jbase))[j4];
        ((float4*)d2s)[idx] = ((const float4*)(d2g + hh * 4096 + jbase))[j4];
    }
    if (t < 128) {
        int h2 = t >> 5, r = t & 31;
        float sv = srcb[h2 * 4096 + i0 + r];
        srcs[h2][r] = sv;
        float sd = sv + dmax[h2];
        rces[h2][r] = -fmaxf(sd, 0.2f * sd);     // -mhat (>= true masked max)
    }
    __syncthreads();
    const float LOG2E = 1.44269504f;
    float s1[2], s2[2];
#pragma unroll
    for (int rt = 0; rt < 2; rt++) {
        float src = srcs[h][rt * 16 + c16], rce = rces[h][rt * 16 + c16];
        s1[rt] = (src + rce) * LOG2E;
        s2[rt] = (0.2f * src + rce) * LOG2E;
    }
    f32x4 acc[2][4];
    f32x4 accl[2] = {(f32x4){0.f, 0.f, 0.f, 0.f}, (f32x4){0.f, 0.f, 0.f, 0.f}};
#pragma unroll
    for (int rt = 0; rt < 2; rt++)
#pragma unroll
        for (int ct = 0; ct < 4; ct++) acc[rt][ct] = (f32x4){0.f, 0.f, 0.f, 0.f};
    uint4 onesu;                                  // B ones-column frag: col c16==0 only
    unsigned os = (c16 == 0) ? 0x3F803F80u : 0u;
    onesu.x = os; onesu.y = os; onesu.z = os; onesu.w = os;
    short8 bfones = __builtin_bit_cast(short8, onesu);
    const uint4* g4 = (const uint4*)whswz;
    size_t b0 = (size_t)(jbase >> 6) * 2048 + h * 512 + (kq * 4 + quad) * 64 + c16;
    uint4 bn[4];
#pragma unroll
    for (int ct = 0; ct < 4; ct++) bn[ct] = g4[b0 + ct * 16];
    for (int step = 0; step < 16; step++) {
        uint4 bc[4];
#pragma unroll
        for (int ct = 0; ct < 4; ct++) bc[ct] = bn[ct];
        if (step < 15) {
            size_t bs = b0 + (size_t)(step + 1) * 2048;
#pragma unroll
            for (int ct = 0; ct < 4; ct++) bn[ct] = g4[bs + ct * 16];
        }
        int jl0 = step * 64 + kq * 32 + quad * 8;
        unsigned int mby[2];
#pragma unroll
        for (int rt = 0; rt < 2; rt++)
            mby[rt] = (unsigned int)(mbs[rt * 16 + c16][step] >> (kq * 32 + quad * 8)) & 0xFFu;
        const f32x2* p1 = (const f32x2*)&d1s[h][jl0];
        const f32x2* p2 = (const f32x2*)&d2s[h][jl0];
        f32x2 d1v[4] = {p1[0], p1[1], p1[2], p1[3]};
        f32x2 d2v[4] = {p2[0], p2[1], p2[2], p2[3]};
        uint4 afu[2];
#pragma unroll
        for (int rt = 0; rt < 2; rt++) {
            unsigned pu[4];
#pragma unroll
            for (int q = 0; q < 4; q++) {
                f32x2 t1 = d1v[q] + s1[rt];
                f32x2 t2 = d2v[q] + s2[rt];
                f32x2 m = __builtin_elementwise_max(t1, t2);
                float ea = exp2f(m.x), eb = exp2f(m.y);
                unsigned v = ((__float_as_uint(ea) + 0x8000u) >> 16) |
                             ((__float_as_uint(eb) + 0x8000u) & 0xFFFF0000u);
                pu[q] = v & mlut[(mby[rt] >> (2 * q)) & 3u];
            }
            afu[rt].x = pu[0]; afu[rt].y = pu[1]; afu[rt].z = pu[2]; afu[rt].w = pu[3];
        }
        short8 af0 = __builtin_bit_cast(short8, afu[0]);
        short8 af1 = __builtin_bit_cast(short8, afu[1]);
#pragma unroll
        for (int ct = 0; ct < 4; ct++) {
            short8 bf = __builtin_bit_cast(short8, bc[ct]);
            acc[0][ct] = __builtin_amdgcn_mfma_f32_16x16x32_bf16(af0, bf, acc[0][ct], 0, 0, 0);
            acc[1][ct] = __builtin_amdgcn_mfma_f32_16x16x32_bf16(af1, bf, acc[1][ct], 0, 0, 0);
        }
        accl[0] = __builtin_amdgcn_mfma_f32_16x16x32_bf16(af0, bfones, accl[0], 0, 0, 0);
        accl[1] = __builtin_amdgcn_mfma_f32_16x16x32_bf16(af1, bfones, accl[1], 0, 0, 0);
    }
    __syncthreads();                              // d1s dead; reuse as accsh
    if (kq == 1) {
#pragma unroll
        for (int rt = 0; rt < 2; rt++) {
#pragma unroll
            for (int ct = 0; ct < 4; ct++)
                accsh[((h * 2 + rt) * 4 + ct) * 64 + lane] = acc[rt][ct];
            if (c16 == 0) *(f32x4*)&lsh[h][rt][quad][0] = accl[rt];
        }
    }
    __syncthreads();
    if (kq == 0) {
        float* out = hnp + (size_t)blockIdx.y * (TOTAL * 256);
#pragma unroll
        for (int rt = 0; rt < 2; rt++) {
#pragma unroll
            for (int ct = 0; ct < 4; ct++) {
                f32x4 o = acc[rt][ct] + accsh[((h * 2 + rt) * 4 + ct) * 64 + lane];
#pragma unroll
                for (int rr = 0; rr < 4; rr++) {  // D: col=lane&15, row=quad*4+rr
                    int row = i0 + rt * 16 + quad * 4 + rr;
                    out[(size_t)row * 256 + h * 64 + ct * 16 + c16] = o[rr];
                }
            }
            if (c16 == 0) {                       // l from ones-column (D col 0)
                f32x4 lv = accl[rt] + *(const f32x4*)&lsh[h][rt][quad][0];
#pragma unroll
                for (int rr = 0; rr < 4; rr++)
                    lpart[(size_t)(blockIdx.y * 4 + h) * 4096 + i0 + rt * 16 + quad * 4 + rr] = lv[rr];
            }
        }
    }
}

// ---------------- h = 0.5*relu((sum partials)/l) + 0.5*h (float4) ---------------------
__global__ void k_epilogue(const float* hnp, const float* lpart, float* h) {
    int idx = blockIdx.x * 256 + threadIdx.x;     // float4 index
    int row = idx >> 6, hh_ = (idx >> 4) & 3;
    float l = 0.f;
#pragma unroll
    for (int js = 0; js < 4; js++)
        l += lpart[(size_t)(js * 4 + hh_) * 4096 + row];
    float inv = 1.f / l;
    const float4* p0 = (const float4*)hnp;
    const float4* p1 = (const float4*)(hnp + (size_t)TOTAL * 256);
    const float4* p2 = (const float4*)(hnp + (size_t)2 * TOTAL * 256);
    const float4* p3 = (const float4*)(hnp + (size_t)3 * TOTAL * 256);
    float4* h4 = (float4*)h;
    float4 a = p0[idx], b = p1[idx], c = p2[idx], d = p3[idx], hh = h4[idx];
    hh.x = 0.5f * fmaxf((a.x + b.x + c.x + d.x) * inv, 0.f) + 0.5f * hh.x;
    hh.y = 0.5f * fmaxf((a.y + b.y + c.y + d.y) * inv, 0.f) + 0.5f * hh.y;
    hh.z = 0.5f * fmaxf((a.z + b.z + c.z + d.z) * inv, 0.f) + 0.5f * hh.z;
    hh.w = 0.5f * fmaxf((a.w + b.w + c.w + d.w) * inv, 0.f) + 0.5f * hh.w;
    h4[idx] = hh;
}

// ---------------- final scores + cos (wave-per-row) -----------------------------------
__global__ __launch_bounds__(256) void k_scores(const float* h, float* scoresv, float* cosv) {
    int t = threadIdx.x, W = t >> 6, lane = t & 63;
    const float4* h4 = (const float4*)h;
    float4 q4 = h4[lane];
    float a = q4.x * q4.x + q4.y * q4.y + q4.z * q4.z + q4.w * q4.w;
    for (int o = 32; o > 0; o >>= 1) a += __shfl_xor(a, o);
    float qn = sqrtf(a) + 1e-8f;
    int gw = blockIdx.x * 4 + W;
    for (int n = gw; n < NDOCS; n += 1024) {
        size_t ro = (size_t)(1 + MD + n) * 64;
        float4 s4 = h4[ro + lane];
        float b = s4.x * s4.x + s4.y * s4.y + s4.z * s4.z + s4.w * s4.w;
        float c = q4.x * s4.x + q4.y * s4.y + q4.z * s4.z + q4.w * s4.w;
        for (int o = 32; o > 0; o >>= 1) { b += __shfl_xor(b, o); c += __shfl_xor(c, o); }
        if (lane == 0) {
            scoresv[n] = c * (1.f / 16.f);
            cosv[n] = c / (qn * (sqrtf(b) + 1e-8f));
        }
    }
}

// ---------------- softmax over scores (single block, 1024 thr) ------------------------
__global__ __launch_bounds__(1024) void k_softmax(const float* scoresv, float* awv) {
    __shared__ float red[16];
    int t = threadIdx.x;
    float m = -__builtin_inff();
    for (int n = t; n < NDOCS; n += 1024) m = fmaxf(m, scoresv[n]);
    for (int o = 32; o > 0; o >>= 1) m = fmaxf(m, __shfl_down(m, o));
    if ((t & 63) == 0) red[t >> 6] = m;
    __syncthreads();
    m = red[0];
#pragma unroll
    for (int i = 1; i < 16; i++) m = fmaxf(m, red[i]);
    __syncthreads();
    float s = 0.f;
    for (int n = t; n < NDOCS; n += 1024) s += __expf(scoresv[n] - m);
    for (int o = 32; o > 0; o >>= 1) s += __shfl_down(s, o);
    if ((t & 63) == 0) red[t >> 6] = s;
    __syncthreads();
    s = 0.f;
#pragma unroll
    for (int i = 0; i < 16; i++) s += red[i];
    float inv = 1.f / s;
    for (int n = t; n < NDOCS; n += 1024) awv[n] = __expf(scoresv[n] - m) * inv;
}

// ---------------- fused feature GEMM + output ----------------------------------------
// feats2[j][r]: inner loop reads 8 rows with 2 broadcast ds_read_b128 per j.
#define TN 8
__global__ __launch_bounds__(256) void k_fusion(const float* h, const float* awv,
                                                const float* cosv, const float* fwT,
                                                const void* fusion_b, const void* out_w,
                                                const void* out_bp, void* outv,
                                                const int* flagp) {
    __shared__ float feats2[514][TN];
    __shared__ float qhs[256];
    __shared__ float red[TN][4];
    int isbf = flagp[0];
    int t = threadIdx.x;
    int n0 = blockIdx.x * TN;
    qhs[t] = h[t];
    __syncthreads();
    for (int idx = t; idx < 514 * TN; idx += 256) {
        int j = idx >> 3, r = idx & 7;
        int n = n0 + r;
        float v = 0.f;
        if (n < NDOCS) {
            if (j < 256) v = h[(size_t)(1 + MD + n) * 256 + j];
            else if (j < 512) v = qhs[j - 256] * (awv[n] + 0.5f);
            else if (j == 512) v = cosv[n];
            else v = awv[n];
        }
        feats2[j][r] = v;
    }
    __syncthreads();
    float acc[TN];
    float bk = ldf(fusion_b, t, isbf);
#pragma unroll
    for (int r = 0; r < TN; r++) acc[r] = bk;
    for (int j0 = 0; j0 < 512; j0 += 8) {        // 8 independent weight loads in flight
        float wv[8];
#pragma unroll
        for (int u = 0; u < 8; u++) wv[u] = fwT[(j0 + u) * 256 + t];
#pragma unroll
        for (int u = 0; u < 8; u++) {
            float4 a = *(const float4*)&feats2[j0 + u][0];
            float4 b = *(const float4*)&feats2[j0 + u][4];
            acc[0] = fmaf(a.x, wv[u], acc[0]);
            acc[1] = fmaf(a.y, wv[u], acc[1]);
            acc[2] = fmaf(a.z, wv[u], acc[2]);
            acc[3] = fmaf(a.w, wv[u], acc[3]);
            acc[4] = fmaf(b.x, wv[u], acc[4]);
            acc[5] = fmaf(b.y, wv[u], acc[5]);
            acc[6] = fmaf(b.z, wv[u], acc[6]);
            acc[7] = fmaf(b.w, wv[u], acc[7]);
        }
    }
#pragma unroll
    for (int j = 512; j < 514; j++) {
        float wv = fwT[j * 256 + t];
#pragma unroll
        for (int r = 0; r < TN; r++) acc[r] = fmaf(feats2[j][r], wv, acc[r]);
    }
    float ow = ldf(out_w, t, isbf);
    float outb = ldf(out_bp, 0, isbf);
#pragma unroll
    for (int r = 0; r < TN; r++) {
        float o = fmaxf(acc[r], 0.f) * ow;
        for (int off = 32; off > 0; off >>= 1) o += __shfl_down(o, off);
        if ((t & 63) == 0) red[r][t >> 6] = o;
    }
    __syncthreads();
    if (t < TN) {
        int n = n0 + t;
        if (n < NDOCS) {
            float o = red[t][0] + red[t][1] + red[t][2] + red[t][3] + outb + 0.5f * cosv[n];
            if (isbf) ((bf16*)outv)[n] = __float2bfloat16(o);
            else      ((float*)outv)[n] = o;
        }
    }
}

extern "C" void kernel_launch(void* const* d_in, const int* in_sizes, int n_in,
                              void* d_out, int out_size, void* d_ws, size_t ws_size,
                              hipStream_t stream) {
    const void* emb      = d_in[0];
    const int*  adj      = (const int*)d_in[1];
    const void* proj_w   = d_in[3];
    const void* proj_b   = d_in[4];
    const void* ln_scale = d_in[5];
    const void* ln_bias  = d_in[6];
    const void* gat_W    = d_in[7];
    const void* gat_a    = d_in[8];
    const void* fusion_w = d_in[9];
    const void* fusion_b = d_in[10];
    const void* out_w    = d_in[11];
    const void* out_b    = d_in[12];

    unsigned long long* maskb = (unsigned long long*)d_ws;
    int* flag = (int*)((char*)d_ws + (size_t)4096 * 64 * 8);
    float* f = (float*)((char*)d_ws + (size_t)4096 * 64 * 8 + 256);
    float* h       = f; f += 4096 * 256;
    float* srcb    = f; f += 4 * 4096;
    float* dstb    = f; f += 4 * 4096;
    float* d1g     = f; f += 4 * 4096;
    float* d2g     = f; f += 4 * 4096;
    float* dmax    = f; f += 64;
    float* projT   = f; f += EMB * 256;
    float* gatT    = f; f += 2 * 256 * 256;
    float* fwT     = f; f += 514 * 256;
    float* scoresv = f; f += 4096;
    float* cosv    = f; f += 4096;
    float* awv     = f; f += 4096;
    float* lpart   = f; f += 4 * 4 * 4096;                 // 256KB
    ushort_t* whswz = (ushort_t*)f; f += 4096 * 256 / 2;   // 2MB
    float* hnp     = f; f += (size_t)JS * 4096 * 256;      // 16MB partials

    k_detect<<<dim3(1), dim3(256), 0, stream>>>((const uint16_t*)emb, flag);
    k_transpose<<<dim3(1410), dim3(256), 0, stream>>>(proj_w, gat_W, fusion_w, projT, gatT, fwT, flag);
    k_adjmask<<<dim3(4096), dim3(256), 0, stream>>>(adj, maskb);
    k_proj<<<dim3(TOTAL / PR), dim3(256), 0, stream>>>(emb, proj_b, projT, h, flag);
    k_cosupdate<<<dim3(256), dim3(256), 0, stream>>>(h);
    for (int layer = 0; layer < 2; layer++) {
        k_ln_wh<<<dim3(TOTAL / LR), dim3(256), 0, stream>>>(h, gatT, ln_scale, ln_bias, gat_a,
                                                            whswz, srcb, dstb, d1g, d2g, layer, flag);
        k_dmax<<<dim3(4), dim3(256), 0, stream>>>(dstb, dmax);
        k_pv<<<dim3(TOTAL / TI, JS), dim3(512), 0, stream>>>(whswz, srcb, dmax, d1g, d2g,
                                                             maskb, hnp, lpart);
        k_epilogue<<<dim3(1024), dim3(256), 0, stream>>>(hnp, lpart, h);
    }
    k_scores<<<dim3(256), dim3(256), 0, stream>>>(h, scoresv, cosv);
    k_softmax<<<dim3(1), dim3(1024), 0, stream>>>(scoresv, awv);
    k_fusion<<<dim3((NDOCS + TN - 1) / TN), dim3(256), 0, stream>>>(h, awv, cosv, fwT,
                                                                    fusion_b, out_w, out_b,
                                                                    (void*)d_out, flag);
}